// Round 10
// baseline (384.541 us; speedup 1.0000x reference)
//
#include <hip/hip_runtime.h>
#include <hip/hip_bf16.h>
#include <math.h>

#define B_    8
#define CIN   32
#define CO    64
#define NN    512
#define TT    24
#define NT    (NN*TT)        /* 12288 */
#define LNCNT (CO*NT)        /* 786432 */
#define EPSL  1e-5f
#define MAXNZ 64
#define HSS   28             /* fp32 LDS row stride (hbuild) */

typedef const float* fp;
static __device__ __forceinline__ float lk(float x){ return x > 0.f ? x : 0.01f*x; }
static __device__ __forceinline__ float sg(float x){
    if(x >= 0.f){ float e = expf(-x); return 1.f/(1.f+e); }
    float e = expf(x); return e/(1.f+e);
}
// bf16 pair pack/unpack (lo = even element, hi = odd element)
static __device__ __forceinline__ unsigned pk2(float a, float b){
    __hip_bfloat16 x = __float2bfloat16(a), y = __float2bfloat16(b);
    unsigned lo = *(unsigned short*)&x, hi = *(unsigned short*)&y;
    return lo | (hi<<16);
}
static __device__ __forceinline__ float lo2f(unsigned u){ return __uint_as_float(u<<16); }
static __device__ __forceinline__ float hi2f(unsigned u){ return __uint_as_float(u & 0xffff0000u); }

// ---- CSC build from adj (2% dense), fully parallel; also emits o_adj copy ----
__global__ __launch_bounds__(256) void k_csc(fp adj, int* cnt, int* idx, float* val,
        float* o_adj){
    int e = blockIdx.x*blockDim.x + threadIdx.x;   // 0 .. NN*NN-1
    if(e >= NN*NN) return;
    float a = adj[e];
    o_adj[e] = a;                                  // replaces the D2D memcpy launch
    if(a != 0.f){
        int u = e >> 9, q = e & 511;
        int slot = atomicAdd(&cnt[q], 1);
        if(slot < MAXNZ){ idx[q*MAXNZ+slot] = u; val[q*MAXNZ+slot] = a; }
    }
}

// load 8 weights w[m][kb..kb+7] (T=24 bounds -> 0 pad), split hi/lo bf16 frags
static __device__ __forceinline__ void ldw_split(fp w, int m, int kb, uint4* hi, uint4* lo){
    float vh[8], vl[8];
    #pragma unroll
    for(int j=0;j<8;++j){
        float v = (m < TT && (kb+j) < TT) ? w[m*TT + kb + j] : 0.f;
        __hip_bfloat16 hb = __float2bfloat16(v);
        float hf = __bfloat162float(hb);
        vh[j] = hf;
        vl[j] = v - hf;
    }
    *hi = make_uint4(pk2(vh[0],vh[1]),pk2(vh[2],vh[3]),pk2(vh[4],vh[5]),pk2(vh[6],vh[7]));
    *lo = make_uint4(pk2(vl[0],vl[1]),pk2(vl[2],vl[3]),pk2(vl[4],vl[5]),pk2(vl[6],vl[7]));
}

// ---- merged one-time weight fragment prep (sage + conv) ----
__global__ __launch_bounds__(256) void k_wprep(fp s0ws, fp s0wn, fp s1ws, fp s1wn, uint4* wf,
        fp w1, fp wt, uint4* wcf){
    int t = threadIdx.x;
    int lane = t & 63, g = t >> 6;
    {   // sage weights
        int M = g >> 1, H = g & 1;
        int m  = H*16 + (lane&15);
        int kb = (lane>>4)*8;
        for(int L=0; L<2; ++L){
            fp w = L ? (M ? s1wn : s1ws) : (M ? s0wn : s0ws);
            uint4 hi, lo;
            ldw_split(w, m, kb, &hi, &lo);
            wf[L*512 + g*128 +      lane] = hi;
            wf[L*512 + g*128 + 64 + lane] = lo;
        }
    }
    {   // conv weights
        int kb = (lane>>4)*8;
        for(int ot=0; ot<4; ++ot){
            int m = ot*16 + (lane&15);
            float vh[8], vl[8];
            #pragma unroll
            for(int j=0;j<8;++j){
                int c = kb+j;
                float v = (g==0) ? w1[m*CIN+c] : wt[(m*CIN+c)*3 + (g-1)];
                __hip_bfloat16 hb = __float2bfloat16(v);
                float hf = __bfloat162float(hb);
                vh[j]=hf; vl[j]=v-hf;
            }
            wcf[ot*512 + g*128 +      lane] = make_uint4(
                pk2(vh[0],vh[1]),pk2(vh[2],vh[3]),pk2(vh[4],vh[5]),pk2(vh[6],vh[7]));
            wcf[ot*512 + g*128 + 64 + lane] = make_uint4(
                pk2(vl[0],vl[1]),pk2(vl[2],vl[3]),pk2(vl[4],vl[5]),pk2(vl[6],vl[7]));
        }
    }
}

typedef __attribute__((ext_vector_type(8))) short bf16x8;
typedef __attribute__((ext_vector_type(4))) float f32x4;
typedef __attribute__((ext_vector_type(2))) float f32x2;

static __device__ __forceinline__ f32x4 MF(uint4 a, uint4 b, f32x4 c){
    union { uint4 u; bf16x8 v; } A, Bv; A.u = a; Bv.u = b;
    return __builtin_amdgcn_mfma_f32_16x16x32_bf16(A.v, Bv.v, c, 0, 0, 0);
}

// ======================= MFMA conv1 + temporal conv + LN stats ================
#define XST 20
__global__ __launch_bounds__(256, 4) void k_conv(fp x, const uint4* wcf, fp b1, fp bt,
        float* xin, float* x1p, float* stats){
    __shared__ __attribute__((aligned(16))) unsigned xh[208*XST];
    __shared__ __attribute__((aligned(16))) unsigned xl[208*XST];
    __shared__ float red[256];
    int bid = blockIdx.x; int b = bid>>6; int n0 = (bid&63)*8;
    int tid = threadIdx.x; int lane = tid&63; int w = tid>>6;
    for(int i=tid;i<3072;i+=256){
        int cp = i/192; int r = i-cp*192; int node = r/24; int t = r-node*24;
        const float* xp = x + ((size_t)(b*CIN + 2*cp)*NN + n0+node)*TT + t;
        float a = xp[0], b2 = xp[NT];
        __hip_bfloat16 ab = __float2bfloat16(a), bb = __float2bfloat16(b2);
        float ah = __bfloat162float(ab), bh = __bfloat162float(bb);
        int row = node*26 + t + 1;
        xh[row*XST+cp] = pk2(ah, bh);
        xl[row*XST+cp] = pk2(a-ah, b2-bh);
    }
    {   // zero guard rows (t=-1 and t=24 per node): 8*2*16 = 256 slots
        int node = tid>>5; int which = (tid>>4)&1; int j = tid&15;
        int row = node*26 + which*25;
        xh[row*XST+j]=0; xl[row*XST+j]=0;
    }
    const uint4* wb = wcf + w*512;
    uint4 h1 = wb[      lane], l1 = wb[ 64+lane];
    uint4 ht0= wb[128 + lane], lt0= wb[192+lane];
    uint4 ht1= wb[256 + lane], lt1= wb[320+lane];
    uint4 ht2= wb[384 + lane], lt2= wb[448+lane];
    int mrow = (lane>>4)*4;
    float bi0[4], bi1[4];
    #pragma unroll
    for(int r2=0;r2<4;++r2){
        int o = w*16 + mrow + r2;
        bi0[r2]=b1[o]; bi1[r2]=bt[o];
    }
    __syncthreads();
    float ls=0.f, lsq=0.f;
    int kb4 = (lane>>4)*4;
    for(int pt=0; pt<12; ++pt){
        int p = pt*16 + (lane&15);
        int node = p/24, t = p-node*24;
        int rc = (node*26 + t + 1)*XST;
        uint4 Bhm = *(const uint4*)&xh[rc - XST + kb4];
        uint4 Blm = *(const uint4*)&xl[rc - XST + kb4];
        uint4 Bhc = *(const uint4*)&xh[rc       + kb4];
        uint4 Blc = *(const uint4*)&xl[rc       + kb4];
        uint4 Bhp = *(const uint4*)&xh[rc + XST + kb4];
        uint4 Blp = *(const uint4*)&xl[rc + XST + kb4];
        f32x4 D0 = {bi0[0],bi0[1],bi0[2],bi0[3]};
        f32x4 D1 = {bi1[0],bi1[1],bi1[2],bi1[3]};
        D0 = MF(h1, Bhc, D0); D0 = MF(l1, Bhc, D0); D0 = MF(h1, Blc, D0);
        D1 = MF(ht0,Bhm, D1); D1 = MF(lt0,Bhm, D1); D1 = MF(ht0,Blm, D1);
        D1 = MF(ht1,Bhc, D1); D1 = MF(lt1,Bhc, D1); D1 = MF(ht1,Blc, D1);
        D1 = MF(ht2,Bhp, D1); D1 = MF(lt2,Bhp, D1); D1 = MF(ht2,Blp, D1);
        size_t gbase = ((size_t)(b*CO + w*16 + mrow)*NN + n0+node)*TT + t;
        #pragma unroll
        for(int r2=0;r2<4;++r2){
            xin[gbase + (size_t)r2*NT] = D0[r2];
            x1p[gbase + (size_t)r2*NT] = D1[r2];
            ls  += D1[r2];
            lsq += D1[r2]*D1[r2];
        }
    }
    red[tid]=ls; __syncthreads();
    for(int s=128;s>0;s>>=1){ if(tid<s) red[tid]+=red[tid+s]; __syncthreads(); }
    float tsum = red[0]; __syncthreads();
    red[tid]=lsq; __syncthreads();
    for(int s=128;s>0;s>>=1){ if(tid<s) red[tid]+=red[tid+s]; __syncthreads(); }
    if(tid==0){ atomicAdd(&stats[b], tsum); atomicAdd(&stats[8+b], red[0]); }
}

// ---- LN+leaky (fused) then h = stack(4*x1, adj^T x1); h stored packed bf16 ----
__global__ __launch_bounds__(512, 4) void k_hbuild(fp x1p, fp lng, fp lnb,
        const float* stats, const int* cnt, const int* idx, const float* val, unsigned* h){
    __shared__ float xs[NN*HSS];          // 57.3 KB
    int blk = blockIdx.x; int b = blk >> 6; int c = blk & 63;
    int tid = threadIdx.x;
    float mm = stats[b] / (float)LNCNT;
    float vv = fmaxf(stats[8+b] / (float)LNCNT - mm*mm, 0.f);
    float m = mm, inv = rsqrtf(vv + EPSL);
    fp src  = x1p + (size_t)(b*CO + c)*NT;
    fp gsrc = lng + (size_t)c*NT;
    fp bsrc = lnb + (size_t)c*NT;
    for(int i4=tid;i4<NT/4;i4+=512){
        int i = i4*4;
        int n = i/TT, t = i-n*TT;
        float4 s  = *(const float4*)(src + i);
        float4 g  = *(const float4*)(gsrc + i);
        float4 bb = *(const float4*)(bsrc + i);
        *(float4*)&xs[n*HSS + t] = make_float4(
            lk((s.x-m)*inv*g.x+bb.x), lk((s.y-m)*inv*g.y+bb.y),
            lk((s.z-m)*inv*g.z+bb.z), lk((s.w-m)*inv*g.w+bb.w));
    }
    int n = tid;
    int c0 = cnt[n];
    int cq = c0 > MAXNZ ? MAXNZ : c0;
    int4 j0 = *(const int4*)&idx[n*MAXNZ+0];   // prefetch (entries >= cq unused)
    int4 j1 = *(const int4*)&idx[n*MAXNZ+4];
    int4 j2 = *(const int4*)&idx[n*MAXNZ+8];
    float4 v0 = *(const float4*)&val[n*MAXNZ+0];
    float4 v1 = *(const float4*)&val[n*MAXNZ+4];
    float4 v2 = *(const float4*)&val[n*MAXNZ+8];
    __syncthreads();
    float acc[TT];
    #pragma unroll
    for(int l=0;l<TT;++l) acc[l]=0.f;
#define HB(J,U,V) if((J)<cq){ const float4* rp=(const float4*)&xs[(U)*HSS]; \
    _Pragma("unroll") for(int k=0;k<6;++k){ float4 wv=rp[k]; \
        acc[4*k]+=(V)*wv.x; acc[4*k+1]+=(V)*wv.y; acc[4*k+2]+=(V)*wv.z; acc[4*k+3]+=(V)*wv.w; } }
    HB(0,j0.x,v0.x) HB(1,j0.y,v0.y) HB(2,j0.z,v0.z) HB(3,j0.w,v0.w)
    HB(4,j1.x,v1.x) HB(5,j1.y,v1.y) HB(6,j1.z,v1.z) HB(7,j1.w,v1.w)
    HB(8,j2.x,v2.x) HB(9,j2.y,v2.y) HB(10,j2.z,v2.z) HB(11,j2.w,v2.w)
    for(int j=12;j<cq;++j){
        int u = idx[n*MAXNZ+j]; float v = val[n*MAXNZ+j];
        const float4* rp = (const float4*)&xs[u*HSS];
        #pragma unroll
        for(int k=0;k<6;++k){ float4 wv=rp[k];
            acc[4*k]+=v*wv.x; acc[4*k+1]+=v*wv.y; acc[4*k+2]+=v*wv.z; acc[4*k+3]+=v*wv.w; }
    }
    float t1[TT];
    const float4* sp = (const float4*)&xs[n*HSS];
    #pragma unroll
    for(int k=0;k<6;++k){
        float4 v = sp[k];
        t1[4*k]=v.x; t1[4*k+1]=v.y; t1[4*k+2]=v.z; t1[4*k+3]=v.w;
    }
    unsigned* h0 = h + (size_t)((b*CO+c)*2)*(NT/2);
    unsigned* h1 = h0 + NT/2;
    #pragma unroll
    for(int k=0;k<3;++k){
        *(uint4*)(h0 + n*12 + 4*k) = make_uint4(
            pk2(4.f*t1[8*k],  4.f*t1[8*k+1]), pk2(4.f*t1[8*k+2],4.f*t1[8*k+3]),
            pk2(4.f*t1[8*k+4],4.f*t1[8*k+5]), pk2(4.f*t1[8*k+6],4.f*t1[8*k+7]));
        *(uint4*)(h1 + n*12 + 4*k) = make_uint4(
            pk2(acc[8*k],  acc[8*k+1]), pk2(acc[8*k+2],acc[8*k+3]),
            pk2(acc[8*k+4],acc[8*k+5]), pk2(acc[8*k+6],acc[8*k+7]));
    }
}

// ======================= MFMA-based fused GraphSAGE x2 =======================
static __device__ __forceinline__ void acc8v(f32x2* t, uint4 q){
    t[0] += (f32x2){lo2f(q.x), hi2f(q.x)};
    t[1] += (f32x2){lo2f(q.y), hi2f(q.y)};
    t[2] += (f32x2){lo2f(q.z), hi2f(q.z)};
    t[3] += (f32x2){lo2f(q.w), hi2f(q.w)};
}

#define GBODY(u) { int ro=(u)*12; \
    uint4 q0=*(const uint4*)&hsb[ro]; \
    uint4 q1=*(const uint4*)&hsb[ro+4]; \
    uint4 q2=*(const uint4*)&hsb[ro+8]; \
    acc8v(t2v,q0); acc8v(t2v+4,q1); acc8v(t2v+8,q2); }
#define GSTEP(J,U) if((J)<cq) GBODY(U)

__global__ __launch_bounds__(512, 4) void k_sageF(unsigned* h, const uint4* wf,
        fp s0b, fp s1b, const int* cnt, const int* idx){
    __shared__ unsigned hsb[NN*12];       // 24 KB, the ONLY buffer
    int tid  = threadIdx.x;
    int lane = tid & 63;
    int wv   = tid >> 6;
    unsigned* base = h + (size_t)blockIdx.x*(NT/2);

    for(int i=tid;i<1536;i+=512) ((uint4*)hsb)[i] = ((const uint4*)base)[i];
    int n  = tid;              // gather: this thread owns node n
    int c0 = cnt[n];
    float di = 1.f / (float)(c0 < 1 ? 1 : c0);
    int cq = c0 > MAXNZ ? MAXNZ : c0;
    int4 i0 = *(const int4*)&idx[n*MAXNZ+0];   // prefetch (entries >= cq unused)
    int4 i1 = *(const int4*)&idx[n*MAXNZ+4];
    int4 i2 = *(const int4*)&idx[n*MAXNZ+8];
    __syncthreads();

    for(int layer=0; layer<2; ++layer){
        const uint4* wl = wf + layer*512;
        uint4 wsHiA = wl[      lane], wsLoA = wl[ 64+lane];
        uint4 wsHiB = wl[128 + lane], wsLoB = wl[192+lane];
        uint4 wnHiA = wl[256 + lane], wnLoA = wl[320+lane];
        uint4 wnHiB = wl[384 + lane], wnLoB = wl[448+lane];
        fp Bp = layer ? s1b : s0b;
        float biA[4], biB[4];
        #pragma unroll
        for(int r=0;r<4;++r){
            biA[r] = Bp[(lane>>4)*4 + r];
            int m2 = 16 + (lane>>4)*4 + r;
            biB[r] = (m2 < TT) ? Bp[m2] : 0.f;
        }

        // ---- phase 1: gather t2 (reads hsb); load B0 frags (own rows) ----
        f32x2 t2v[12];
        #pragma unroll
        for(int l=0;l<12;++l) t2v[l] = (f32x2){0.f,0.f};
        GSTEP(0,i0.x) GSTEP(1,i0.y) GSTEP(2,i0.z) GSTEP(3,i0.w)
        GSTEP(4,i1.x) GSTEP(5,i1.y) GSTEP(6,i1.z) GSTEP(7,i1.w)
        GSTEP(8,i2.x) GSTEP(9,i2.y) GSTEP(10,i2.z) GSTEP(11,i2.w)
        for(int j=12;j<cq;++j){ int u=idx[n*MAXNZ+j]; GBODY(u) }
        #pragma unroll
        for(int l=0;l<12;++l) t2v[l] *= di;

        uint4 b0[4];
        #pragma unroll
        for(int i=0;i<4;++i) b0[i]=make_uint4(0,0,0,0);
        if(lane < 48){
            #pragma unroll
            for(int i=0;i<4;++i){
                int nn_ = wv*64 + i*16 + (lane&15);
                b0[i] = *(const uint4*)&hsb[nn_*12 + ((lane>>4)<<2)];
            }
        }
        __syncthreads();   // ALL hsb reads (gather + B0, all waves) complete

        // ---- t2 pack -> own hsb row (input slab now dead) ----
        *(uint4*)&hsb[n*12  ] = make_uint4(
            pk2(t2v[0].x,t2v[0].y), pk2(t2v[1].x,t2v[1].y),
            pk2(t2v[2].x,t2v[2].y), pk2(t2v[3].x,t2v[3].y));
        *(uint4*)&hsb[n*12+4] = make_uint4(
            pk2(t2v[4].x,t2v[4].y), pk2(t2v[5].x,t2v[5].y),
            pk2(t2v[6].x,t2v[6].y), pk2(t2v[7].x,t2v[7].y));
        *(uint4*)&hsb[n*12+8] = make_uint4(
            pk2(t2v[8].x,t2v[8].y), pk2(t2v[9].x,t2v[9].y),
            pk2(t2v[10].x,t2v[10].y), pk2(t2v[11].x,t2v[11].y));
        __syncthreads();   // t2 rows visible

        // ---- phase 2: B1 frags (own rows), 32 MFMAs, pack, D -> own rows ----
        uint4 b1[4];
        #pragma unroll
        for(int i=0;i<4;++i) b1[i]=make_uint4(0,0,0,0);
        if(lane < 48){
            #pragma unroll
            for(int i=0;i<4;++i){
                int nn_ = wv*64 + i*16 + (lane&15);
                b1[i] = *(const uint4*)&hsb[nn_*12 + ((lane>>4)<<2)];
            }
        }
        uint2 pa[4], pb[4];
        #pragma unroll
        for(int i=0;i<4;++i){
            f32x4 Da = {biA[0],biA[1],biA[2],biA[3]};
            f32x4 Db = {biB[0],biB[1],biB[2],biB[3]};
            Da = MF(wsHiA, b0[i], Da);
            Da = MF(wsLoA, b0[i], Da);
            Da = MF(wnHiA, b1[i], Da);
            Da = MF(wnLoA, b1[i], Da);
            Db = MF(wsHiB, b0[i], Db);
            Db = MF(wsLoB, b0[i], Db);
            Db = MF(wnHiB, b1[i], Db);
            Db = MF(wnLoB, b1[i], Db);
            pa[i] = make_uint2(pk2(Da[0],Da[1]), pk2(Da[2],Da[3]));
            pb[i] = make_uint2(pk2(Db[0],Db[1]), pk2(Db[2],Db[3]));
        }
        __syncthreads();   // all B1 reads done before D overwrites rows
        #pragma unroll
        for(int i=0;i<4;++i){
            int nn_ = wv*64 + i*16 + (lane&15);
            int o = (lane>>4)*2;           // uints {0,2,4,6}: m = 2o..2o+3
            *(uint2*)&hsb[nn_*12 + o] = pa[i];
            if(lane < 32){                 // m = 16..23 -> uints {8,10}
                *(uint2*)&hsb[nn_*12 + 8 + (lane>>4)*2] = pb[i];
            }
        }
        __syncthreads();   // D visible for next layer's gather / writeback
    }
    for(int i=tid;i<1536;i+=512) ((uint4*)base)[i] = ((const uint4*)hsb)[i];
}

// ---- merged f1+f2: blocks [0,512) = f1 role, [512,1024) = f2 ----
#define F2S 25
__global__ __launch_bounds__(256) void k_f12(const unsigned* h, fp w1, fp w2,
        float* f1, float* f2){
    __shared__ float red[256*F2S];
    int tid = threadIdx.x;
    if(blockIdx.x < 512){
        // f1[b,l,n] = sum_c sg(gate)*lk(filt)*w1[c]
        if(tid < 192){
            int blk = blockIdx.x; int b = blk>>6; int n0 = (blk&63)*8;
            float acc = 0.f;
            const unsigned* fb = h + (size_t)b*CO*NT + n0*12;
            const unsigned* gb = fb + (size_t)CO*(NT/2);
            int e = tid;
            for(int c=0;c<CO;++c){
                float w = w1[c];
                unsigned f = fb[(size_t)c*(NT/2) + (e>>1)];
                unsigned g = gb[(size_t)c*(NT/2) + (e>>1)];
                float fv = (e&1) ? hi2f(f) : lo2f(f);
                float gv = (e&1) ? hi2f(g) : lo2f(g);
                acc += sg(gv)*lk(fv)*w;
            }
            int nl = e/TT, t = e%TT;
            f1[(b*TT+t)*NN + n0+nl] = acc;
        }
        return;
    }
    // f2[b,c,l] = sum_n sg(gate)*lk(filt)*w2[n]
    int blk = blockIdx.x - 512; int b = blk/CO; int c = blk%CO;
    float acc[TT];
    #pragma unroll
    for(int l=0;l<TT;++l) acc[l]=0.f;
    const unsigned* fb = h + (size_t)b*CO*NT + (size_t)c*(NT/2);
    const unsigned* gb = fb + (size_t)CO*(NT/2);
    for(int n=tid;n<NN;n+=256){
        float w = w2[n];
        #pragma unroll
        for(int k=0;k<3;++k){
            uint4 f = *(const uint4*)(fb + n*12 + 4*k);
            uint4 g = *(const uint4*)(gb + n*12 + 4*k);
            acc[8*k  ] += sg(lo2f(g.x))*lk(lo2f(f.x))*w;
            acc[8*k+1] += sg(hi2f(g.x))*lk(hi2f(f.x))*w;
            acc[8*k+2] += sg(lo2f(g.y))*lk(lo2f(f.y))*w;
            acc[8*k+3] += sg(hi2f(g.y))*lk(hi2f(f.y))*w;
            acc[8*k+4] += sg(lo2f(g.z))*lk(lo2f(f.z))*w;
            acc[8*k+5] += sg(hi2f(g.z))*lk(hi2f(f.z))*w;
            acc[8*k+6] += sg(lo2f(g.w))*lk(lo2f(f.w))*w;
            acc[8*k+7] += sg(hi2f(g.w))*lk(hi2f(f.w))*w;
        }
    }
    #pragma unroll
    for(int l=0;l<TT;++l) red[tid*F2S+l]=acc[l];
    __syncthreads();
    for(int s=128;s>0;s>>=1){
        if(tid<s){
            #pragma unroll
            for(int l=0;l<TT;++l) red[tid*F2S+l]+=red[(tid+s)*F2S+l];
        }
        __syncthreads();
    }
    if(tid<TT) f2[(b*CO+c)*TT+tid] = red[tid];
}

// ---------------- dilated(2) conv over n on f1 ; split 4x over n ----------------
__global__ __launch_bounds__(256) void k_conv_f1(fp f1, fp wd1, float* f1c){
    __shared__ float fs[TT][130];
    __shared__ float w0[TT*TT], w1a[TT*TT];
    int bid = blockIdx.x; int b = bid>>2; int n0 = (bid&3)*128;
    int tid=threadIdx.x;
    for(int i=tid;i<TT*130;i+=256){
        int l=i/130, col=i%130; int n = n0+col-1;
        fs[l][col] = (n>=0 && n<NN) ? f1[(b*TT+l)*NN+n] : 0.f;
    }
    for(int i=tid;i<TT*TT;i+=256){ w0[i]=wd1[i*2]; w1a[i]=wd1[i*2+1]; }
    __syncthreads();
    for(int j=tid;j<TT*128;j+=256){
        int o=j>>7, nn=j&127;
        float acc=0.f;
        #pragma unroll
        for(int i=0;i<TT;++i) acc += fs[i][nn]*w0[o*TT+i] + fs[i][nn+2]*w1a[o*TT+i];
        f1c[(b*TT+o)*NN+n0+nn]=acc;
    }
}

// ---------------- dilated(2) conv over l on f2 ----------------
__global__ __launch_bounds__(256) void k_conv_f2(fp f2, fp wd2, float* f2c){
    __shared__ float fs[CO][TT+2];
    __shared__ float w0[CO*CO], w1a[CO*CO];
    int b = blockIdx.x; int tid=threadIdx.x;
    for(int i=tid;i<CO*TT;i+=256){ int c=i/TT,l=i%TT; fs[c][l+1]=f2[(b*CO+c)*TT+l]; }
    for(int c=tid;c<CO;c+=256){ fs[c][0]=0.f; fs[c][TT+1]=0.f; }
    for(int i=tid;i<CO*CO;i+=256){ w0[i]=wd2[i*2]; w1a[i]=wd2[i*2+1]; }
    __syncthreads();
    for(int j=tid;j<CO*TT;j+=256){
        int o=j/TT, l=j%TT;
        float acc=0.f;
        for(int i=0;i<CO;++i) acc += fs[i][l]*w0[o*CO+i] + fs[i][l+2]*w1a[o*CO+i];
        f2c[(b*CO+o)*TT+l]=acc;
    }
}

// ---------------- g1[b,l,c] = sum_n f1c[b,l,n]*tW[n,c] ----------------
__global__ __launch_bounds__(384) void k_g1(fp f1c, fp tW, float* g1){
    __shared__ float fs[6*NN];
    int blk=blockIdx.x; int b=blk>>2; int part=blk&3;
    int tid=threadIdx.x;
    for(int i=tid;i<6*NN;i+=384) fs[i]=f1c[b*TT*NN + part*6*NN + i];
    __syncthreads();
    int c = tid & 63; int r = tid >> 6;   // r = 0..5
    float acc=0.f;
    for(int n=0;n<NN;++n) acc += fs[r*NN + n]*tW[n*CO + c];
    g1[(b*TT + part*6 + r)*CO + c] = acc;
}

// -------- logits: A = parallel sig matmul; BC = t_v matmul + BN + softmax ------
__global__ __launch_bounds__(256) void k_lgA(fp g1, fp f2c, fp tbias, float* sig){
    int j = blockIdx.x*256 + threadIdx.x;
    int b=j/(TT*TT); int r=j%(TT*TT); int l=r/TT; int q=r%TT;
    float acc = tbias[l*TT+q];
    fp gg = g1 + (b*TT+l)*CO;
    fp ff = f2c + b*CO*TT + q;
    for(int c=0;c<CO;++c) acc += gg[c]*ff[c*TT];
    sig[j] = sg(acc);
}
// round 10: lgB+lgC merged (lg2 lives in LDS; same per-output FMA order)
__global__ __launch_bounds__(256) void k_lgBC(fp tv, const float* sig,
        fp bng, fp bnb, float* coefs, float* tco){
    __shared__ float lg2[B_*TT*TT];       // 18.4 KB
    __shared__ float muq[TT], scq[TT], shq[TT];
    int tid=threadIdx.x;
    for(int j=tid;j<B_*TT*TT;j+=256){
        int b=j/(TT*TT); int r=j%(TT*TT); int l=r/TT; int q=r%TT;
        float acc=0.f;
        for(int k=0;k<TT;++k) acc += tv[l*TT+k]*sig[(b*TT+k)*TT+q];
        lg2[j]=acc;
    }
    __syncthreads();
    if(tid<TT){
        int q=tid;
        float s=0.f;
        for(int b=0;b<B_;++b) for(int l=0;l<TT;++l) s += lg2[(b*TT+l)*TT+q];
        float mu = s/192.f;
        float v=0.f;
        for(int b=0;b<B_;++b) for(int l=0;l<TT;++l){ float d = lg2[(b*TT+l)*TT+q]-mu; v += d*d; }
        v = fmaxf(v/192.f, 0.f);
        muq[q]=mu; scq[q]=rsqrtf(v+EPSL)*bng[q]; shq[q]=bnb[q];
    }
    __syncthreads();
    if(tid<192){
        int b=tid/TT, l=tid%TT;
        int base = (l<12)?0:12;
        float z[12];
        float mx=-1e30f;
        #pragma unroll
        for(int r=0;r<12;++r){
            int q=base+r;
            float zv=(lg2[(b*TT+l)*TT+q]-muq[q])*scq[q]+shq[q];
            z[r]=zv; mx = fmaxf(mx,zv);
        }
        float s=0.f;
        #pragma unroll
        for(int r=0;r<12;++r){ z[r]=expf(z[r]-mx); s+=z[r]; }
        float is=1.f/s;
        for(int q=0;q<TT;++q){
            float cf = (q>=base && q<base+12) ? z[q-base]*is : 0.f;
            coefs[(b*TT+l)*TT+q]=cf;
            tco[(b*TT+q)*TT+l]=cf;
        }
    }
}

// ---- x1new = xg @ coefs^T ; y = leaky(x1new)+x_input ; LN stats ----
// Round 10: latency fix. (a) cf read as float4 rows (144 b128 broadcast reads
// instead of 576 b32 -> 4x less LDS-pipe time); (b) 2 threads per node, each
// computing 12 q's (row-unpack duplicated; 2048 blocks x 256 thr = 8192 waves
// = 100% occupancy potential, was capped at 50%). Per-q FMA chain order
// unchanged (l ascending) -> output values bit-identical; ls/lsq partials
// regroup only within the already-nondeterministic atomic stats path.
__global__ __launch_bounds__(256, 4) void k_apply(const unsigned* h, fp xin, fp coefs,
        float* y, float* stats){
    __shared__ __attribute__((aligned(16))) float cf[TT*TT];
    __shared__ float red[256];
    int blk=blockIdx.x; int b=blk>>8; int c=(blk>>2)&63; int quar=blk&3;
    int tid=threadIdx.x;
    for(int i=tid;i<TT*TT;i+=256) cf[i]=coefs[b*TT*TT+i];
    __syncthreads();
    int nl = tid & 127, qh = tid >> 7;       // qh: which 12-q half
    int n = quar*128 + nl;
    const unsigned* fb = h + (size_t)b*CO*NT + (size_t)c*(NT/2) + n*12;
    const unsigned* gb = fb + (size_t)CO*(NT/2);
    fp xrow = xin + (size_t)(b*CO+c)*NT + n*TT + qh*12;
    float* yrow = y + (size_t)(b*CO+c)*NT + n*TT + qh*12;
    float row[TT];
    #pragma unroll
    for(int k=0;k<3;++k){
        uint4 f = *(const uint4*)(fb + 4*k);
        uint4 g = *(const uint4*)(gb + 4*k);
        row[8*k  ] = sg(lo2f(g.x))*lk(lo2f(f.x));
        row[8*k+1] = sg(hi2f(g.x))*lk(hi2f(f.x));
        row[8*k+2] = sg(lo2f(g.y))*lk(lo2f(f.y));
        row[8*k+3] = sg(hi2f(g.y))*lk(hi2f(f.y));
        row[8*k+4] = sg(lo2f(g.z))*lk(lo2f(f.z));
        row[8*k+5] = sg(hi2f(g.z))*lk(hi2f(f.z));
        row[8*k+6] = sg(lo2f(g.w))*lk(lo2f(f.w));
        row[8*k+7] = sg(hi2f(g.w))*lk(hi2f(f.w));
    }
    float ls=0.f, lsq=0.f;
    #pragma unroll
    for(int k=0;k<3;++k){
        float4 u = *(const float4*)(xrow + 4*k);
        float a[4];
        #pragma unroll
        for(int j=0;j<4;++j){
            int q = qh*12 + 4*k + j;
            const float4* crow = (const float4*)&cf[q*TT];
            float acc=0.f;
            #pragma unroll
            for(int kk=0;kk<6;++kk){
                float4 cv = crow[kk];
                acc += row[4*kk  ]*cv.x;
                acc += row[4*kk+1]*cv.y;
                acc += row[4*kk+2]*cv.z;
                acc += row[4*kk+3]*cv.w;
            }
            a[j]=acc;
        }
        float y0 = lk(a[0])+u.x, y1 = lk(a[1])+u.y, y2 = lk(a[2])+u.z, y3 = lk(a[3])+u.w;
        *(float4*)(yrow + 4*k) = make_float4(y0,y1,y2,y3);
        ls  += y0+y1+y2+y3;
        lsq += y0*y0+y1*y1+y2*y2+y3*y3;
    }
    red[tid]=ls; __syncthreads();
    for(int s=128;s>0;s>>=1){ if(tid<s) red[tid]+=red[tid+s]; __syncthreads(); }
    float t0=red[0]; __syncthreads();
    red[tid]=lsq; __syncthreads();
    for(int s=128;s>0;s>>=1){ if(tid<s) red[tid]+=red[tid+s]; __syncthreads(); }
    if(tid==0){ atomicAdd(&stats[32+b], t0); atomicAdd(&stats[40+b], red[0]); }
}

// ---------------- final LN apply; stats finalize inlined ----------------
__global__ void k_final(fp y, fp lng, fp lnb, const float* stats, float* out){
    float mb[8], sb[8];
    #pragma unroll
    for(int b=0;b<8;++b){
        float mm = stats[32+b] / (float)LNCNT;
        float vv = fmaxf(stats[40+b] / (float)LNCNT - mm*mm, 0.f);
        mb[b]=mm; sb[b]=rsqrtf(vv + EPSL);
    }
    int tot = B_*CO*NT;
    for(int i = blockIdx.x*blockDim.x + threadIdx.x; i<tot; i+=gridDim.x*blockDim.x){
        int b = i/LNCNT; int r = i%LNCNT;
        out[i] = (y[i]-mb[b])*sb[b]*lng[r]+lnb[r];
    }
}

extern "C" void kernel_launch(void* const* d_in, const int* in_sizes, int n_in,
                              void* d_out, int out_size, void* d_ws, size_t ws_size,
                              hipStream_t stream){
    fp x    = (fp)d_in[0];
    fp adj  = (fp)d_in[1];
    fp w1   = (fp)d_in[2];
    fp b1   = (fp)d_in[3];
    fp wt   = (fp)d_in[4];
    fp bt   = (fp)d_in[5];
    fp lng  = (fp)d_in[6];
    fp lnb  = (fp)d_in[7];
    fp s0ws = (fp)d_in[8];
    fp s0wn = (fp)d_in[9];
    fp s0b  = (fp)d_in[10];
    fp s1ws = (fp)d_in[11];
    fp s1wn = (fp)d_in[12];
    fp s1b  = (fp)d_in[13];
    fp tw1  = (fp)d_in[14];
    fp tw2  = (fp)d_in[15];
    fp twd1 = (fp)d_in[16];
    fp twd2 = (fp)d_in[17];
    fp tW   = (fp)d_in[18];
    fp tbias= (fp)d_in[19];
    fp tv   = (fp)d_in[20];
    fp bng  = (fp)d_in[21];
    fp bnb  = (fp)d_in[22];

    float* W = (float*)d_ws;            // stats [0..63]
    int*   CNTp = (int*)(W+256);        // 512 ints (zeroed each launch)
    int*   IDXp = (int*)(W+1280);
    float* VALp = W+34048;
    float* F1   = W+66816;
    float* F1C  = W+165120;
    float* F2   = W+263424;
    float* F2C  = W+275712;
    float* G1   = W+288000;
    float* CF   = W+300288;
    float* XIN  = W+304896;
    float* X1   = W+6596352;
    float* SIG  = W+6596352;            // reuse X1 head (dead after hbuild)
    uint4* WFq  = (uint4*)(W+12887808); // sage weight frags: 1024 uint4 = 16KB
    uint4* WCF  = (uint4*)(W+12891904); // conv weight frags: 2048 uint4 = 32KB
    unsigned* HA = (unsigned*)(W+19179264);   // packed bf16 h: 6291456 uints
    float* Y    = W+31762176;           // ends 38053632 floats = 152.2 MB

    float* oout   = (float*)d_out;
    float* o_adj  = oout + 6291456;
    float* o_tc   = oout + 6291456 + 262144;

    hipMemsetAsync(W, 0, 768*sizeof(float), stream);   // stats + cnt
    k_csc<<<1024,256,0,stream>>>(adj, CNTp, IDXp, VALp, o_adj);
    k_wprep<<<1,256,0,stream>>>(s0ws, s0wn, s1ws, s1wn, WFq, w1, wt, WCF);
    k_conv<<<512,256,0,stream>>>(x, WCF, b1, bt, XIN, X1, W);
    k_hbuild<<<512,512,0,stream>>>(X1, lng, lnb, W, CNTp, IDXp, VALp, HA);
    k_sageF<<<1024,512,0,stream>>>(HA, WFq, s0b, s1b, CNTp, IDXp);
    k_f12<<<1024,256,0,stream>>>(HA, tw1, tw2, F1, F2);
    k_conv_f1<<<32,256,0,stream>>>(F1, twd1, F1C);
    k_conv_f2<<<8,256,0,stream>>>(F2, twd2, F2C);
    k_g1<<<32,384,0,stream>>>(F1C, tW, G1);
    k_lgA<<<18,256,0,stream>>>(G1, F2C, tbias, SIG);
    k_lgBC<<<1,256,0,stream>>>(tv, SIG, bng, bnb, CF, o_tc);
    k_apply<<<2048,256,0,stream>>>(HA, XIN, CF, Y, W);
    k_final<<<2048,256,0,stream>>>(Y, lng, lnb, W, oout);
}

// Round 11
// 362.947 us; speedup vs baseline: 1.0595x; 1.0595x over previous
//
#include <hip/hip_runtime.h>
#include <hip/hip_bf16.h>
#include <math.h>

#define B_    8
#define CIN   32
#define CO    64
#define NN    512
#define TT    24
#define NT    (NN*TT)        /* 12288 */
#define LNCNT (CO*NT)        /* 786432 */
#define EPSL  1e-5f
#define MAXNZ 64
#define HSS   28             /* fp32 LDS row stride (hbuild) */

typedef const float* fp;
static __device__ __forceinline__ float lk(float x){ return x > 0.f ? x : 0.01f*x; }
static __device__ __forceinline__ float sg(float x){
    if(x >= 0.f){ float e = expf(-x); return 1.f/(1.f+e); }
    float e = expf(x); return e/(1.f+e);
}
// bf16 pair pack/unpack (lo = even element, hi = odd element)
static __device__ __forceinline__ unsigned pk2(float a, float b){
    __hip_bfloat16 x = __float2bfloat16(a), y = __float2bfloat16(b);
    unsigned lo = *(unsigned short*)&x, hi = *(unsigned short*)&y;
    return lo | (hi<<16);
}
static __device__ __forceinline__ float lo2f(unsigned u){ return __uint_as_float(u<<16); }
static __device__ __forceinline__ float hi2f(unsigned u){ return __uint_as_float(u & 0xffff0000u); }

// ---- CSC build from adj (2% dense), fully parallel; also emits o_adj copy ----
__global__ __launch_bounds__(256) void k_csc(fp adj, int* cnt, int* idx, float* val,
        float* o_adj){
    int e = blockIdx.x*blockDim.x + threadIdx.x;   // 0 .. NN*NN-1
    if(e >= NN*NN) return;
    float a = adj[e];
    o_adj[e] = a;                                  // replaces the D2D memcpy launch
    if(a != 0.f){
        int u = e >> 9, q = e & 511;
        int slot = atomicAdd(&cnt[q], 1);
        if(slot < MAXNZ){ idx[q*MAXNZ+slot] = u; val[q*MAXNZ+slot] = a; }
    }
}

// load 8 weights w[m][kb..kb+7] (T=24 bounds -> 0 pad), split hi/lo bf16 frags
static __device__ __forceinline__ void ldw_split(fp w, int m, int kb, uint4* hi, uint4* lo){
    float vh[8], vl[8];
    #pragma unroll
    for(int j=0;j<8;++j){
        float v = (m < TT && (kb+j) < TT) ? w[m*TT + kb + j] : 0.f;
        __hip_bfloat16 hb = __float2bfloat16(v);
        float hf = __bfloat162float(hb);
        vh[j] = hf;
        vl[j] = v - hf;
    }
    *hi = make_uint4(pk2(vh[0],vh[1]),pk2(vh[2],vh[3]),pk2(vh[4],vh[5]),pk2(vh[6],vh[7]));
    *lo = make_uint4(pk2(vl[0],vl[1]),pk2(vl[2],vl[3]),pk2(vl[4],vl[5]),pk2(vl[6],vl[7]));
}

// ---- merged one-time weight fragment prep (sage + conv) ----
__global__ __launch_bounds__(256) void k_wprep(fp s0ws, fp s0wn, fp s1ws, fp s1wn, uint4* wf,
        fp w1, fp wt, uint4* wcf){
    int t = threadIdx.x;
    int lane = t & 63, g = t >> 6;
    {   // sage weights
        int M = g >> 1, H = g & 1;
        int m  = H*16 + (lane&15);
        int kb = (lane>>4)*8;
        for(int L=0; L<2; ++L){
            fp w = L ? (M ? s1wn : s1ws) : (M ? s0wn : s0ws);
            uint4 hi, lo;
            ldw_split(w, m, kb, &hi, &lo);
            wf[L*512 + g*128 +      lane] = hi;
            wf[L*512 + g*128 + 64 + lane] = lo;
        }
    }
    {   // conv weights
        int kb = (lane>>4)*8;
        for(int ot=0; ot<4; ++ot){
            int m = ot*16 + (lane&15);
            float vh[8], vl[8];
            #pragma unroll
            for(int j=0;j<8;++j){
                int c = kb+j;
                float v = (g==0) ? w1[m*CIN+c] : wt[(m*CIN+c)*3 + (g-1)];
                __hip_bfloat16 hb = __float2bfloat16(v);
                float hf = __bfloat162float(hb);
                vh[j]=hf; vl[j]=v-hf;
            }
            wcf[ot*512 + g*128 +      lane] = make_uint4(
                pk2(vh[0],vh[1]),pk2(vh[2],vh[3]),pk2(vh[4],vh[5]),pk2(vh[6],vh[7]));
            wcf[ot*512 + g*128 + 64 + lane] = make_uint4(
                pk2(vl[0],vl[1]),pk2(vl[2],vl[3]),pk2(vl[4],vl[5]),pk2(vl[6],vl[7]));
        }
    }
}

typedef __attribute__((ext_vector_type(8))) short bf16x8;
typedef __attribute__((ext_vector_type(4))) float f32x4;
typedef __attribute__((ext_vector_type(2))) float f32x2;

static __device__ __forceinline__ f32x4 MF(uint4 a, uint4 b, f32x4 c){
    union { uint4 u; bf16x8 v; } A, Bv; A.u = a; Bv.u = b;
    return __builtin_amdgcn_mfma_f32_16x16x32_bf16(A.v, Bv.v, c, 0, 0, 0);
}

// ======================= MFMA conv1 + temporal conv + LN stats ================
#define XST 20
__global__ __launch_bounds__(256, 4) void k_conv(fp x, const uint4* wcf, fp b1, fp bt,
        float* xin, float* x1p, float* stats){
    __shared__ __attribute__((aligned(16))) unsigned xh[208*XST];
    __shared__ __attribute__((aligned(16))) unsigned xl[208*XST];
    __shared__ float red[256];
    int bid = blockIdx.x; int b = bid>>6; int n0 = (bid&63)*8;
    int tid = threadIdx.x; int lane = tid&63; int w = tid>>6;
    for(int i=tid;i<3072;i+=256){
        int cp = i/192; int r = i-cp*192; int node = r/24; int t = r-node*24;
        const float* xp = x + ((size_t)(b*CIN + 2*cp)*NN + n0+node)*TT + t;
        float a = xp[0], b2 = xp[NT];
        __hip_bfloat16 ab = __float2bfloat16(a), bb = __float2bfloat16(b2);
        float ah = __bfloat162float(ab), bh = __bfloat162float(bb);
        int row = node*26 + t + 1;
        xh[row*XST+cp] = pk2(ah, bh);
        xl[row*XST+cp] = pk2(a-ah, b2-bh);
    }
    {   // zero guard rows (t=-1 and t=24 per node): 8*2*16 = 256 slots
        int node = tid>>5; int which = (tid>>4)&1; int j = tid&15;
        int row = node*26 + which*25;
        xh[row*XST+j]=0; xl[row*XST+j]=0;
    }
    const uint4* wb = wcf + w*512;
    uint4 h1 = wb[      lane], l1 = wb[ 64+lane];
    uint4 ht0= wb[128 + lane], lt0= wb[192+lane];
    uint4 ht1= wb[256 + lane], lt1= wb[320+lane];
    uint4 ht2= wb[384 + lane], lt2= wb[448+lane];
    int mrow = (lane>>4)*4;
    float bi0[4], bi1[4];
    #pragma unroll
    for(int r2=0;r2<4;++r2){
        int o = w*16 + mrow + r2;
        bi0[r2]=b1[o]; bi1[r2]=bt[o];
    }
    __syncthreads();
    float ls=0.f, lsq=0.f;
    int kb4 = (lane>>4)*4;
    for(int pt=0; pt<12; ++pt){
        int p = pt*16 + (lane&15);
        int node = p/24, t = p-node*24;
        int rc = (node*26 + t + 1)*XST;
        uint4 Bhm = *(const uint4*)&xh[rc - XST + kb4];
        uint4 Blm = *(const uint4*)&xl[rc - XST + kb4];
        uint4 Bhc = *(const uint4*)&xh[rc       + kb4];
        uint4 Blc = *(const uint4*)&xl[rc       + kb4];
        uint4 Bhp = *(const uint4*)&xh[rc + XST + kb4];
        uint4 Blp = *(const uint4*)&xl[rc + XST + kb4];
        f32x4 D0 = {bi0[0],bi0[1],bi0[2],bi0[3]};
        f32x4 D1 = {bi1[0],bi1[1],bi1[2],bi1[3]};
        D0 = MF(h1, Bhc, D0); D0 = MF(l1, Bhc, D0); D0 = MF(h1, Blc, D0);
        D1 = MF(ht0,Bhm, D1); D1 = MF(lt0,Bhm, D1); D1 = MF(ht0,Blm, D1);
        D1 = MF(ht1,Bhc, D1); D1 = MF(lt1,Bhc, D1); D1 = MF(ht1,Blc, D1);
        D1 = MF(ht2,Bhp, D1); D1 = MF(lt2,Bhp, D1); D1 = MF(ht2,Blp, D1);
        size_t gbase = ((size_t)(b*CO + w*16 + mrow)*NN + n0+node)*TT + t;
        #pragma unroll
        for(int r2=0;r2<4;++r2){
            xin[gbase + (size_t)r2*NT] = D0[r2];
            x1p[gbase + (size_t)r2*NT] = D1[r2];
            ls  += D1[r2];
            lsq += D1[r2]*D1[r2];
        }
    }
    red[tid]=ls; __syncthreads();
    for(int s=128;s>0;s>>=1){ if(tid<s) red[tid]+=red[tid+s]; __syncthreads(); }
    float tsum = red[0]; __syncthreads();
    red[tid]=lsq; __syncthreads();
    for(int s=128;s>0;s>>=1){ if(tid<s) red[tid]+=red[tid+s]; __syncthreads(); }
    if(tid==0){ atomicAdd(&stats[b], tsum); atomicAdd(&stats[8+b], red[0]); }
}

// ---- LN+leaky (fused) then h = stack(4*x1, adj^T x1); h stored packed bf16 ----
__global__ __launch_bounds__(512, 4) void k_hbuild(fp x1p, fp lng, fp lnb,
        const float* stats, const int* cnt, const int* idx, const float* val, unsigned* h){
    __shared__ float xs[NN*HSS];          // 57.3 KB
    int blk = blockIdx.x; int b = blk >> 6; int c = blk & 63;
    int tid = threadIdx.x;
    float mm = stats[b] / (float)LNCNT;
    float vv = fmaxf(stats[8+b] / (float)LNCNT - mm*mm, 0.f);
    float m = mm, inv = rsqrtf(vv + EPSL);
    fp src  = x1p + (size_t)(b*CO + c)*NT;
    fp gsrc = lng + (size_t)c*NT;
    fp bsrc = lnb + (size_t)c*NT;
    for(int i4=tid;i4<NT/4;i4+=512){
        int i = i4*4;
        int n = i/TT, t = i-n*TT;
        float4 s  = *(const float4*)(src + i);
        float4 g  = *(const float4*)(gsrc + i);
        float4 bb = *(const float4*)(bsrc + i);
        *(float4*)&xs[n*HSS + t] = make_float4(
            lk((s.x-m)*inv*g.x+bb.x), lk((s.y-m)*inv*g.y+bb.y),
            lk((s.z-m)*inv*g.z+bb.z), lk((s.w-m)*inv*g.w+bb.w));
    }
    int n = tid;
    int c0 = cnt[n];
    int cq = c0 > MAXNZ ? MAXNZ : c0;
    int4 j0 = *(const int4*)&idx[n*MAXNZ+0];   // prefetch (entries >= cq unused)
    int4 j1 = *(const int4*)&idx[n*MAXNZ+4];
    int4 j2 = *(const int4*)&idx[n*MAXNZ+8];
    float4 v0 = *(const float4*)&val[n*MAXNZ+0];
    float4 v1 = *(const float4*)&val[n*MAXNZ+4];
    float4 v2 = *(const float4*)&val[n*MAXNZ+8];
    __syncthreads();
    float acc[TT];
    #pragma unroll
    for(int l=0;l<TT;++l) acc[l]=0.f;
#define HB(J,U,V) if((J)<cq){ const float4* rp=(const float4*)&xs[(U)*HSS]; \
    _Pragma("unroll") for(int k=0;k<6;++k){ float4 wv=rp[k]; \
        acc[4*k]+=(V)*wv.x; acc[4*k+1]+=(V)*wv.y; acc[4*k+2]+=(V)*wv.z; acc[4*k+3]+=(V)*wv.w; } }
    HB(0,j0.x,v0.x) HB(1,j0.y,v0.y) HB(2,j0.z,v0.z) HB(3,j0.w,v0.w)
    HB(4,j1.x,v1.x) HB(5,j1.y,v1.y) HB(6,j1.z,v1.z) HB(7,j1.w,v1.w)
    HB(8,j2.x,v2.x) HB(9,j2.y,v2.y) HB(10,j2.z,v2.z) HB(11,j2.w,v2.w)
    for(int j=12;j<cq;++j){
        int u = idx[n*MAXNZ+j]; float v = val[n*MAXNZ+j];
        const float4* rp = (const float4*)&xs[u*HSS];
        #pragma unroll
        for(int k=0;k<6;++k){ float4 wv=rp[k];
            acc[4*k]+=v*wv.x; acc[4*k+1]+=v*wv.y; acc[4*k+2]+=v*wv.z; acc[4*k+3]+=v*wv.w; }
    }
    float t1[TT];
    const float4* sp = (const float4*)&xs[n*HSS];
    #pragma unroll
    for(int k=0;k<6;++k){
        float4 v = sp[k];
        t1[4*k]=v.x; t1[4*k+1]=v.y; t1[4*k+2]=v.z; t1[4*k+3]=v.w;
    }
    unsigned* h0 = h + (size_t)((b*CO+c)*2)*(NT/2);
    unsigned* h1 = h0 + NT/2;
    #pragma unroll
    for(int k=0;k<3;++k){
        *(uint4*)(h0 + n*12 + 4*k) = make_uint4(
            pk2(4.f*t1[8*k],  4.f*t1[8*k+1]), pk2(4.f*t1[8*k+2],4.f*t1[8*k+3]),
            pk2(4.f*t1[8*k+4],4.f*t1[8*k+5]), pk2(4.f*t1[8*k+6],4.f*t1[8*k+7]));
        *(uint4*)(h1 + n*12 + 4*k) = make_uint4(
            pk2(acc[8*k],  acc[8*k+1]), pk2(acc[8*k+2],acc[8*k+3]),
            pk2(acc[8*k+4],acc[8*k+5]), pk2(acc[8*k+6],acc[8*k+7]));
    }
}

// ======================= MFMA-based fused GraphSAGE x2 =======================
static __device__ __forceinline__ void acc8v(f32x2* t, uint4 q){
    t[0] += (f32x2){lo2f(q.x), hi2f(q.x)};
    t[1] += (f32x2){lo2f(q.y), hi2f(q.y)};
    t[2] += (f32x2){lo2f(q.z), hi2f(q.z)};
    t[3] += (f32x2){lo2f(q.w), hi2f(q.w)};
}

#define GBODY(u) { int ro=(u)*12; \
    uint4 q0=*(const uint4*)&hsb[ro]; \
    uint4 q1=*(const uint4*)&hsb[ro+4]; \
    uint4 q2=*(const uint4*)&hsb[ro+8]; \
    acc8v(t2v,q0); acc8v(t2v+4,q1); acc8v(t2v+8,q2); }
#define GSTEP(J,U) if((J)<cq) GBODY(U)

__global__ __launch_bounds__(512, 4) void k_sageF(unsigned* h, const uint4* wf,
        fp s0b, fp s1b, const int* cnt, const int* idx){
    __shared__ unsigned hsb[NN*12];       // 24 KB, the ONLY buffer
    int tid  = threadIdx.x;
    int lane = tid & 63;
    int wv   = tid >> 6;
    unsigned* base = h + (size_t)blockIdx.x*(NT/2);

    for(int i=tid;i<1536;i+=512) ((uint4*)hsb)[i] = ((const uint4*)base)[i];
    int n  = tid;              // gather: this thread owns node n
    int c0 = cnt[n];
    float di = 1.f / (float)(c0 < 1 ? 1 : c0);
    int cq = c0 > MAXNZ ? MAXNZ : c0;
    int4 i0 = *(const int4*)&idx[n*MAXNZ+0];   // prefetch (entries >= cq unused)
    int4 i1 = *(const int4*)&idx[n*MAXNZ+4];
    int4 i2 = *(const int4*)&idx[n*MAXNZ+8];
    __syncthreads();

    for(int layer=0; layer<2; ++layer){
        const uint4* wl = wf + layer*512;
        uint4 wsHiA = wl[      lane], wsLoA = wl[ 64+lane];
        uint4 wsHiB = wl[128 + lane], wsLoB = wl[192+lane];
        uint4 wnHiA = wl[256 + lane], wnLoA = wl[320+lane];
        uint4 wnHiB = wl[384 + lane], wnLoB = wl[448+lane];
        fp Bp = layer ? s1b : s0b;
        float biA[4], biB[4];
        #pragma unroll
        for(int r=0;r<4;++r){
            biA[r] = Bp[(lane>>4)*4 + r];
            int m2 = 16 + (lane>>4)*4 + r;
            biB[r] = (m2 < TT) ? Bp[m2] : 0.f;
        }

        // ---- phase 1: gather t2 (reads hsb); load B0 frags (own rows) ----
        f32x2 t2v[12];
        #pragma unroll
        for(int l=0;l<12;++l) t2v[l] = (f32x2){0.f,0.f};
        GSTEP(0,i0.x) GSTEP(1,i0.y) GSTEP(2,i0.z) GSTEP(3,i0.w)
        GSTEP(4,i1.x) GSTEP(5,i1.y) GSTEP(6,i1.z) GSTEP(7,i1.w)
        GSTEP(8,i2.x) GSTEP(9,i2.y) GSTEP(10,i2.z) GSTEP(11,i2.w)
        for(int j=12;j<cq;++j){ int u=idx[n*MAXNZ+j]; GBODY(u) }
        #pragma unroll
        for(int l=0;l<12;++l) t2v[l] *= di;

        uint4 b0[4];
        #pragma unroll
        for(int i=0;i<4;++i) b0[i]=make_uint4(0,0,0,0);
        if(lane < 48){
            #pragma unroll
            for(int i=0;i<4;++i){
                int nn_ = wv*64 + i*16 + (lane&15);
                b0[i] = *(const uint4*)&hsb[nn_*12 + ((lane>>4)<<2)];
            }
        }
        __syncthreads();   // ALL hsb reads (gather + B0, all waves) complete

        // ---- t2 pack -> own hsb row (input slab now dead) ----
        *(uint4*)&hsb[n*12  ] = make_uint4(
            pk2(t2v[0].x,t2v[0].y), pk2(t2v[1].x,t2v[1].y),
            pk2(t2v[2].x,t2v[2].y), pk2(t2v[3].x,t2v[3].y));
        *(uint4*)&hsb[n*12+4] = make_uint4(
            pk2(t2v[4].x,t2v[4].y), pk2(t2v[5].x,t2v[5].y),
            pk2(t2v[6].x,t2v[6].y), pk2(t2v[7].x,t2v[7].y));
        *(uint4*)&hsb[n*12+8] = make_uint4(
            pk2(t2v[8].x,t2v[8].y), pk2(t2v[9].x,t2v[9].y),
            pk2(t2v[10].x,t2v[10].y), pk2(t2v[11].x,t2v[11].y));
        __syncthreads();   // t2 rows visible

        // ---- phase 2: B1 frags (own rows), 32 MFMAs, pack, D -> own rows ----
        uint4 b1[4];
        #pragma unroll
        for(int i=0;i<4;++i) b1[i]=make_uint4(0,0,0,0);
        if(lane < 48){
            #pragma unroll
            for(int i=0;i<4;++i){
                int nn_ = wv*64 + i*16 + (lane&15);
                b1[i] = *(const uint4*)&hsb[nn_*12 + ((lane>>4)<<2)];
            }
        }
        uint2 pa[4], pb[4];
        #pragma unroll
        for(int i=0;i<4;++i){
            f32x4 Da = {biA[0],biA[1],biA[2],biA[3]};
            f32x4 Db = {biB[0],biB[1],biB[2],biB[3]};
            Da = MF(wsHiA, b0[i], Da);
            Da = MF(wsLoA, b0[i], Da);
            Da = MF(wnHiA, b1[i], Da);
            Da = MF(wnLoA, b1[i], Da);
            Db = MF(wsHiB, b0[i], Db);
            Db = MF(wsLoB, b0[i], Db);
            Db = MF(wnHiB, b1[i], Db);
            Db = MF(wnLoB, b1[i], Db);
            pa[i] = make_uint2(pk2(Da[0],Da[1]), pk2(Da[2],Da[3]));
            pb[i] = make_uint2(pk2(Db[0],Db[1]), pk2(Db[2],Db[3]));
        }
        __syncthreads();   // all B1 reads done before D overwrites rows
        #pragma unroll
        for(int i=0;i<4;++i){
            int nn_ = wv*64 + i*16 + (lane&15);
            int o = (lane>>4)*2;           // uints {0,2,4,6}: m = 2o..2o+3
            *(uint2*)&hsb[nn_*12 + o] = pa[i];
            if(lane < 32){                 // m = 16..23 -> uints {8,10}
                *(uint2*)&hsb[nn_*12 + 8 + (lane>>4)*2] = pb[i];
            }
        }
        __syncthreads();   // D visible for next layer's gather / writeback
    }
    for(int i=tid;i<1536;i+=512) ((uint4*)base)[i] = ((const uint4*)hsb)[i];
}

// ---- merged f1+f2: blocks [0,512) = f1 role, [512,1024) = f2 ----
#define F2S 25
__global__ __launch_bounds__(256) void k_f12(const unsigned* h, fp w1, fp w2,
        float* f1, float* f2){
    __shared__ float red[256*F2S];
    int tid = threadIdx.x;
    if(blockIdx.x < 512){
        // f1[b,l,n] = sum_c sg(gate)*lk(filt)*w1[c]
        if(tid < 192){
            int blk = blockIdx.x; int b = blk>>6; int n0 = (blk&63)*8;
            float acc = 0.f;
            const unsigned* fb = h + (size_t)b*CO*NT + n0*12;
            const unsigned* gb = fb + (size_t)CO*(NT/2);
            int e = tid;
            for(int c=0;c<CO;++c){
                float w = w1[c];
                unsigned f = fb[(size_t)c*(NT/2) + (e>>1)];
                unsigned g = gb[(size_t)c*(NT/2) + (e>>1)];
                float fv = (e&1) ? hi2f(f) : lo2f(f);
                float gv = (e&1) ? hi2f(g) : lo2f(g);
                acc += sg(gv)*lk(fv)*w;
            }
            int nl = e/TT, t = e%TT;
            f1[(b*TT+t)*NN + n0+nl] = acc;
        }
        return;
    }
    // f2[b,c,l] = sum_n sg(gate)*lk(filt)*w2[n]
    int blk = blockIdx.x - 512; int b = blk/CO; int c = blk%CO;
    float acc[TT];
    #pragma unroll
    for(int l=0;l<TT;++l) acc[l]=0.f;
    const unsigned* fb = h + (size_t)b*CO*NT + (size_t)c*(NT/2);
    const unsigned* gb = fb + (size_t)CO*(NT/2);
    for(int n=tid;n<NN;n+=256){
        float w = w2[n];
        #pragma unroll
        for(int k=0;k<3;++k){
            uint4 f = *(const uint4*)(fb + n*12 + 4*k);
            uint4 g = *(const uint4*)(gb + n*12 + 4*k);
            acc[8*k  ] += sg(lo2f(g.x))*lk(lo2f(f.x))*w;
            acc[8*k+1] += sg(hi2f(g.x))*lk(hi2f(f.x))*w;
            acc[8*k+2] += sg(lo2f(g.y))*lk(lo2f(f.y))*w;
            acc[8*k+3] += sg(hi2f(g.y))*lk(hi2f(f.y))*w;
            acc[8*k+4] += sg(lo2f(g.z))*lk(lo2f(f.z))*w;
            acc[8*k+5] += sg(hi2f(g.z))*lk(hi2f(f.z))*w;
            acc[8*k+6] += sg(lo2f(g.w))*lk(lo2f(f.w))*w;
            acc[8*k+7] += sg(hi2f(g.w))*lk(hi2f(f.w))*w;
        }
    }
    #pragma unroll
    for(int l=0;l<TT;++l) red[tid*F2S+l]=acc[l];
    __syncthreads();
    for(int s=128;s>0;s>>=1){
        if(tid<s){
            #pragma unroll
            for(int l=0;l<TT;++l) red[tid*F2S+l]+=red[(tid+s)*F2S+l];
        }
        __syncthreads();
    }
    if(tid<TT) f2[(b*CO+c)*TT+tid] = red[tid];
}

// ---------------- dilated(2) conv over n on f1 ; split 4x over n ----------------
__global__ __launch_bounds__(256) void k_conv_f1(fp f1, fp wd1, float* f1c){
    __shared__ float fs[TT][130];
    __shared__ float w0[TT*TT], w1a[TT*TT];
    int bid = blockIdx.x; int b = bid>>2; int n0 = (bid&3)*128;
    int tid=threadIdx.x;
    for(int i=tid;i<TT*130;i+=256){
        int l=i/130, col=i%130; int n = n0+col-1;
        fs[l][col] = (n>=0 && n<NN) ? f1[(b*TT+l)*NN+n] : 0.f;
    }
    for(int i=tid;i<TT*TT;i+=256){ w0[i]=wd1[i*2]; w1a[i]=wd1[i*2+1]; }
    __syncthreads();
    for(int j=tid;j<TT*128;j+=256){
        int o=j>>7, nn=j&127;
        float acc=0.f;
        #pragma unroll
        for(int i=0;i<TT;++i) acc += fs[i][nn]*w0[o*TT+i] + fs[i][nn+2]*w1a[o*TT+i];
        f1c[(b*TT+o)*NN+n0+nn]=acc;
    }
}

// ---------------- dilated(2) conv over l on f2 ----------------
__global__ __launch_bounds__(256) void k_conv_f2(fp f2, fp wd2, float* f2c){
    __shared__ float fs[CO][TT+2];
    __shared__ float w0[CO*CO], w1a[CO*CO];
    int b = blockIdx.x; int tid=threadIdx.x;
    for(int i=tid;i<CO*TT;i+=256){ int c=i/TT,l=i%TT; fs[c][l+1]=f2[(b*CO+c)*TT+l]; }
    for(int c=tid;c<CO;c+=256){ fs[c][0]=0.f; fs[c][TT+1]=0.f; }
    for(int i=tid;i<CO*CO;i+=256){ w0[i]=wd2[i*2]; w1a[i]=wd2[i*2+1]; }
    __syncthreads();
    for(int j=tid;j<CO*TT;j+=256){
        int o=j/TT, l=j%TT;
        float acc=0.f;
        for(int i=0;i<CO;++i) acc += fs[i][l]*w0[o*CO+i] + fs[i][l+2]*w1a[o*CO+i];
        f2c[(b*CO+o)*TT+l]=acc;
    }
}

// ---------------- g1[b,l,c] = sum_n f1c[b,l,n]*tW[n,c] ----------------
__global__ __launch_bounds__(384) void k_g1(fp f1c, fp tW, float* g1){
    __shared__ float fs[6*NN];
    int blk=blockIdx.x; int b=blk>>2; int part=blk&3;
    int tid=threadIdx.x;
    for(int i=tid;i<6*NN;i+=384) fs[i]=f1c[b*TT*NN + part*6*NN + i];
    __syncthreads();
    int c = tid & 63; int r = tid >> 6;   // r = 0..5
    float acc=0.f;
    for(int n=0;n<NN;++n) acc += fs[r*NN + n]*tW[n*CO + c];
    g1[(b*TT + part*6 + r)*CO + c] = acc;
}

// -------- logits: A = sig matmul (18 blk); B = t_v matmul (18 blk); C = BN+softmax --
__global__ __launch_bounds__(256) void k_lgA(fp g1, fp f2c, fp tbias, float* sig){
    int j = blockIdx.x*256 + threadIdx.x;
    int b=j/(TT*TT); int r=j%(TT*TT); int l=r/TT; int q=r%TT;
    float acc = tbias[l*TT+q];
    fp gg = g1 + (b*TT+l)*CO;
    fp ff = f2c + b*CO*TT + q;
    for(int c=0;c<CO;++c) acc += gg[c]*ff[c*TT];
    sig[j] = sg(acc);
}
__global__ __launch_bounds__(256) void k_lgB(fp tv, const float* sig, float* lg2){
    int j = blockIdx.x*256 + threadIdx.x;
    int b=j/(TT*TT); int r=j%(TT*TT); int l=r/TT; int q=r%TT;
    float acc=0.f;
    for(int k=0;k<TT;++k) acc += tv[l*TT+k]*sig[(b*TT+k)*TT+q];
    lg2[j]=acc;
}
__global__ __launch_bounds__(256) void k_lgC(const float* lg2, fp bng, fp bnb,
        float* coefs, float* tco){
    __shared__ float muq[TT], scq[TT], shq[TT];
    int tid=threadIdx.x;
    if(tid<TT){
        int q=tid;
        float s=0.f;
        for(int b=0;b<B_;++b) for(int l=0;l<TT;++l) s += lg2[(b*TT+l)*TT+q];
        float mu = s/192.f;
        float v=0.f;
        for(int b=0;b<B_;++b) for(int l=0;l<TT;++l){ float d = lg2[(b*TT+l)*TT+q]-mu; v += d*d; }
        v = fmaxf(v/192.f, 0.f);
        muq[q]=mu; scq[q]=rsqrtf(v+EPSL)*bng[q]; shq[q]=bnb[q];
    }
    __syncthreads();
    if(tid<192){
        int b=tid/TT, l=tid%TT;
        int base = (l<12)?0:12;
        float z[12];
        float mx=-1e30f;
        #pragma unroll
        for(int r=0;r<12;++r){
            int q=base+r;
            float zv=(lg2[(b*TT+l)*TT+q]-muq[q])*scq[q]+shq[q];
            z[r]=zv; mx = fmaxf(mx,zv);
        }
        float s=0.f;
        #pragma unroll
        for(int r=0;r<12;++r){ z[r]=expf(z[r]-mx); s+=z[r]; }
        float is=1.f/s;
        for(int q=0;q<TT;++q){
            float cf = (q>=base && q<base+12) ? z[q-base]*is : 0.f;
            coefs[(b*TT+l)*TT+q]=cf;
            tco[(b*TT+q)*TT+l]=cf;
        }
    }
}

// ---- x1new = xg @ coefs^T ; y = leaky(x1new)+x_input ; LN stats ----
// Round 11: REVERT to round-9 decomposition (1024 blocks, 1 node/thread,
// 24 q/thread — measured 58us) keeping ONLY the float4-cf read improvement
// (576 -> 144 LDS instructions; per-accumulator l-ascending FMA chain
// unchanged -> bit-identical). Round-10's 2-thr/node split regressed
// (duplicated transcendental unpack + 2x block overhead, occupancy 37%).
__global__ __launch_bounds__(256, 4) void k_apply(const unsigned* h, fp xin, fp coefs,
        float* y, float* stats){
    __shared__ __attribute__((aligned(16))) float cf[TT*TT];
    __shared__ float red[256];
    int blk=blockIdx.x; int b=blk>>7; int c=(blk>>1)&63; int half=blk&1;
    int tid=threadIdx.x;
    for(int i=tid;i<TT*TT;i+=256) cf[i]=coefs[b*TT*TT+i];
    __syncthreads();
    int n = half*256 + tid;
    const unsigned* fb = h + (size_t)b*CO*NT + (size_t)c*(NT/2) + n*12;
    const unsigned* gb = fb + (size_t)CO*(NT/2);
    fp xrow = xin + (size_t)(b*CO+c)*NT + n*TT;
    float* yrow = y + (size_t)(b*CO+c)*NT + n*TT;
    float row[TT];
    #pragma unroll
    for(int k=0;k<3;++k){
        uint4 f = *(const uint4*)(fb + 4*k);
        uint4 g = *(const uint4*)(gb + 4*k);
        row[8*k  ] = sg(lo2f(g.x))*lk(lo2f(f.x));
        row[8*k+1] = sg(hi2f(g.x))*lk(hi2f(f.x));
        row[8*k+2] = sg(lo2f(g.y))*lk(lo2f(f.y));
        row[8*k+3] = sg(hi2f(g.y))*lk(hi2f(f.y));
        row[8*k+4] = sg(lo2f(g.z))*lk(lo2f(f.z));
        row[8*k+5] = sg(hi2f(g.z))*lk(hi2f(f.z));
        row[8*k+6] = sg(lo2f(g.w))*lk(lo2f(f.w));
        row[8*k+7] = sg(hi2f(g.w))*lk(hi2f(f.w));
    }
    float ls=0.f, lsq=0.f;
    #pragma unroll
    for(int k=0;k<6;++k){
        float4 u = *(const float4*)(xrow + 4*k);
        float a[4];
        #pragma unroll
        for(int j=0;j<4;++j){
            const float4* crow = (const float4*)&cf[(4*k+j)*TT];
            float acc=0.f;
            #pragma unroll
            for(int kk=0;kk<6;++kk){
                float4 cv = crow[kk];
                acc += row[4*kk  ]*cv.x;
                acc += row[4*kk+1]*cv.y;
                acc += row[4*kk+2]*cv.z;
                acc += row[4*kk+3]*cv.w;
            }
            a[j]=acc;
        }
        float y0 = lk(a[0])+u.x, y1 = lk(a[1])+u.y, y2 = lk(a[2])+u.z, y3 = lk(a[3])+u.w;
        *(float4*)(yrow + 4*k) = make_float4(y0,y1,y2,y3);
        ls  += y0+y1+y2+y3;
        lsq += y0*y0+y1*y1+y2*y2+y3*y3;
    }
    red[tid]=ls; __syncthreads();
    for(int s=128;s>0;s>>=1){ if(tid<s) red[tid]+=red[tid+s]; __syncthreads(); }
    float t0=red[0]; __syncthreads();
    red[tid]=lsq; __syncthreads();
    for(int s=128;s>0;s>>=1){ if(tid<s) red[tid]+=red[tid+s]; __syncthreads(); }
    if(tid==0){ atomicAdd(&stats[32+b], t0); atomicAdd(&stats[40+b], red[0]); }
}

// ---------------- final LN apply; stats finalize inlined ----------------
__global__ void k_final(fp y, fp lng, fp lnb, const float* stats, float* out){
    float mb[8], sb[8];
    #pragma unroll
    for(int b=0;b<8;++b){
        float mm = stats[32+b] / (float)LNCNT;
        float vv = fmaxf(stats[40+b] / (float)LNCNT - mm*mm, 0.f);
        mb[b]=mm; sb[b]=rsqrtf(vv + EPSL);
    }
    int tot = B_*CO*NT;
    for(int i = blockIdx.x*blockDim.x + threadIdx.x; i<tot; i+=gridDim.x*blockDim.x){
        int b = i/LNCNT; int r = i%LNCNT;
        out[i] = (y[i]-mb[b])*sb[b]*lng[r]+lnb[r];
    }
}

extern "C" void kernel_launch(void* const* d_in, const int* in_sizes, int n_in,
                              void* d_out, int out_size, void* d_ws, size_t ws_size,
                              hipStream_t stream){
    fp x    = (fp)d_in[0];
    fp adj  = (fp)d_in[1];
    fp w1   = (fp)d_in[2];
    fp b1   = (fp)d_in[3];
    fp wt   = (fp)d_in[4];
    fp bt   = (fp)d_in[5];
    fp lng  = (fp)d_in[6];
    fp lnb  = (fp)d_in[7];
    fp s0ws = (fp)d_in[8];
    fp s0wn = (fp)d_in[9];
    fp s0b  = (fp)d_in[10];
    fp s1ws = (fp)d_in[11];
    fp s1wn = (fp)d_in[12];
    fp s1b  = (fp)d_in[13];
    fp tw1  = (fp)d_in[14];
    fp tw2  = (fp)d_in[15];
    fp twd1 = (fp)d_in[16];
    fp twd2 = (fp)d_in[17];
    fp tW   = (fp)d_in[18];
    fp tbias= (fp)d_in[19];
    fp tv   = (fp)d_in[20];
    fp bng  = (fp)d_in[21];
    fp bnb  = (fp)d_in[22];

    float* W = (float*)d_ws;            // stats [0..63]
    int*   CNTp = (int*)(W+256);        // 512 ints (zeroed each launch)
    int*   IDXp = (int*)(W+1280);
    float* VALp = W+34048;
    float* F1   = W+66816;
    float* F1C  = W+165120;
    float* F2   = W+263424;
    float* F2C  = W+275712;
    float* G1   = W+288000;
    float* CF   = W+300288;
    float* XIN  = W+304896;
    float* X1   = W+6596352;
    float* SIG  = W+6596352;            // reuse X1 head (dead after hbuild)
    uint4* WFq  = (uint4*)(W+12887808); // sage weight frags: 1024 uint4 = 16KB
    uint4* WCF  = (uint4*)(W+12891904); // conv weight frags: 2048 uint4 = 32KB
    unsigned* HA = (unsigned*)(W+19179264);   // packed bf16 h: 6291456 uints
    float* Y    = W+31762176;           // ends 38053632 floats = 152.2 MB
    float* LG2  = SIG + 4608;

    float* oout   = (float*)d_out;
    float* o_adj  = oout + 6291456;
    float* o_tc   = oout + 6291456 + 262144;

    hipMemsetAsync(W, 0, 768*sizeof(float), stream);   // stats + cnt
    k_csc<<<1024,256,0,stream>>>(adj, CNTp, IDXp, VALp, o_adj);
    k_wprep<<<1,256,0,stream>>>(s0ws, s0wn, s1ws, s1wn, WFq, w1, wt, WCF);
    k_conv<<<512,256,0,stream>>>(x, WCF, b1, bt, XIN, X1, W);
    k_hbuild<<<512,512,0,stream>>>(X1, lng, lnb, W, CNTp, IDXp, VALp, HA);
    k_sageF<<<1024,512,0,stream>>>(HA, WFq, s0b, s1b, CNTp, IDXp);
    k_f12<<<1024,256,0,stream>>>(HA, tw1, tw2, F1, F2);
    k_conv_f1<<<32,256,0,stream>>>(F1, twd1, F1C);
    k_conv_f2<<<8,256,0,stream>>>(F2, twd2, F2C);
    k_g1<<<32,384,0,stream>>>(F1C, tW, G1);
    k_lgA<<<18,256,0,stream>>>(G1, F2C, tbias, SIG);
    k_lgB<<<18,256,0,stream>>>(tv, SIG, LG2);
    k_lgC<<<1,256,0,stream>>>(LG2, bng, bnb, CF, o_tc);
    k_apply<<<1024,256,0,stream>>>(HA, XIN, CF, Y, W);
    k_final<<<2048,256,0,stream>>>(Y, lng, lnb, W, oout);
}

// Round 13
// 353.419 us; speedup vs baseline: 1.0881x; 1.0270x over previous
//
#include <hip/hip_runtime.h>
#include <hip/hip_bf16.h>
#include <math.h>

#define B_    8
#define CIN   32
#define CO    64
#define NN    512
#define TT    24
#define NT    (NN*TT)        /* 12288 */
#define LNCNT (CO*NT)        /* 786432 */
#define EPSL  1e-5f
#define MAXNZ 64
#define HSS   28             /* fp32 LDS row stride (hbuild) */

typedef const float* fp;
static __device__ __forceinline__ float lk(float x){ return x > 0.f ? x : 0.01f*x; }
static __device__ __forceinline__ float sg(float x){
    if(x >= 0.f){ float e = expf(-x); return 1.f/(1.f+e); }
    float e = expf(x); return e/(1.f+e);
}
// bf16 pair pack/unpack (lo = even element, hi = odd element)
static __device__ __forceinline__ unsigned pk2(float a, float b){
    __hip_bfloat16 x = __float2bfloat16(a), y = __float2bfloat16(b);
    unsigned lo = *(unsigned short*)&x, hi = *(unsigned short*)&y;
    return lo | (hi<<16);
}
static __device__ __forceinline__ float lo2f(unsigned u){ return __uint_as_float(u<<16); }
static __device__ __forceinline__ float hi2f(unsigned u){ return __uint_as_float(u & 0xffff0000u); }

// load 8 weights w[m][kb..kb+7] (T=24 bounds -> 0 pad), split hi/lo bf16 frags
static __device__ __forceinline__ void ldw_split(fp w, int m, int kb, uint4* hi, uint4* lo){
    float vh[8], vl[8];
    #pragma unroll
    for(int j=0;j<8;++j){
        float v = (m < TT && (kb+j) < TT) ? w[m*TT + kb + j] : 0.f;
        __hip_bfloat16 hb = __float2bfloat16(v);
        float hf = __bfloat162float(hb);
        vh[j] = hf;
        vl[j] = v - hf;
    }
    *hi = make_uint4(pk2(vh[0],vh[1]),pk2(vh[2],vh[3]),pk2(vh[4],vh[5]),pk2(vh[6],vh[7]));
    *lo = make_uint4(pk2(vl[0],vl[1]),pk2(vl[2],vl[3]),pk2(vl[4],vl[5]),pk2(vl[6],vl[7]));
}

// ---- merged CSC build (blocks 0..1023) + weight frag prep (block 1024) ----
// NOTE (round 12 lesson): NO cooperative launches in this harness — graph
// capture rejects them silently (final kernel never ran, absmax=6.0).
__global__ __launch_bounds__(256) void k_cscw(fp adj, int* cnt, int* idx, float* val,
        float* o_adj, fp s0ws, fp s0wn, fp s1ws, fp s1wn, uint4* wf,
        fp w1, fp wt, uint4* wcf){
    if(blockIdx.x < 1024){
        int e = blockIdx.x*256 + threadIdx.x;   // 0 .. NN*NN-1 exactly
        float a = adj[e];
        o_adj[e] = a;                           // replaces the D2D memcpy launch
        if(a != 0.f){
            int u = e >> 9, q = e & 511;
            int slot = atomicAdd(&cnt[q], 1);
            if(slot < MAXNZ){ idx[q*MAXNZ+slot] = u; val[q*MAXNZ+slot] = a; }
        }
        return;
    }
    int t = threadIdx.x;
    int lane = t & 63, g = t >> 6;
    {   // sage weights
        int M = g >> 1, H = g & 1;
        int m  = H*16 + (lane&15);
        int kb = (lane>>4)*8;
        for(int L=0; L<2; ++L){
            fp w = L ? (M ? s1wn : s1ws) : (M ? s0wn : s0ws);
            uint4 hi, lo;
            ldw_split(w, m, kb, &hi, &lo);
            wf[L*512 + g*128 +      lane] = hi;
            wf[L*512 + g*128 + 64 + lane] = lo;
        }
    }
    {   // conv weights
        int kb = (lane>>4)*8;
        for(int ot=0; ot<4; ++ot){
            int m = ot*16 + (lane&15);
            float vh[8], vl[8];
            #pragma unroll
            for(int j=0;j<8;++j){
                int c = kb+j;
                float v = (g==0) ? w1[m*CIN+c] : wt[(m*CIN+c)*3 + (g-1)];
                __hip_bfloat16 hb = __float2bfloat16(v);
                float hf = __bfloat162float(hb);
                vh[j]=hf; vl[j]=v-hf;
            }
            wcf[ot*512 + g*128 +      lane] = make_uint4(
                pk2(vh[0],vh[1]),pk2(vh[2],vh[3]),pk2(vh[4],vh[5]),pk2(vh[6],vh[7]));
            wcf[ot*512 + g*128 + 64 + lane] = make_uint4(
                pk2(vl[0],vl[1]),pk2(vl[2],vl[3]),pk2(vl[4],vl[5]),pk2(vl[6],vl[7]));
        }
    }
}

typedef __attribute__((ext_vector_type(8))) short bf16x8;
typedef __attribute__((ext_vector_type(4))) float f32x4;
typedef __attribute__((ext_vector_type(2))) float f32x2;

static __device__ __forceinline__ f32x4 MF(uint4 a, uint4 b, f32x4 c){
    union { uint4 u; bf16x8 v; } A, Bv; A.u = a; Bv.u = b;
    return __builtin_amdgcn_mfma_f32_16x16x32_bf16(A.v, Bv.v, c, 0, 0, 0);
}

// ======================= MFMA conv1 + temporal conv + LN stats ================
#define XST 20
__global__ __launch_bounds__(256, 4) void k_conv(fp x, const uint4* wcf, fp b1, fp bt,
        float* xin, float* x1p, float* stats){
    __shared__ __attribute__((aligned(16))) unsigned xh[208*XST];
    __shared__ __attribute__((aligned(16))) unsigned xl[208*XST];
    __shared__ float red[256];
    int bid = blockIdx.x; int b = bid>>6; int n0 = (bid&63)*8;
    int tid = threadIdx.x; int lane = tid&63; int w = tid>>6;
    for(int i=tid;i<3072;i+=256){
        int cp = i/192; int r = i-cp*192; int node = r/24; int t = r-node*24;
        const float* xp = x + ((size_t)(b*CIN + 2*cp)*NN + n0+node)*TT + t;
        float a = xp[0], b2 = xp[NT];
        __hip_bfloat16 ab = __float2bfloat16(a), bb = __float2bfloat16(b2);
        float ah = __bfloat162float(ab), bh = __bfloat162float(bb);
        int row = node*26 + t + 1;
        xh[row*XST+cp] = pk2(ah, bh);
        xl[row*XST+cp] = pk2(a-ah, b2-bh);
    }
    {   // zero guard rows (t=-1 and t=24 per node): 8*2*16 = 256 slots
        int node = tid>>5; int which = (tid>>4)&1; int j = tid&15;
        int row = node*26 + which*25;
        xh[row*XST+j]=0; xl[row*XST+j]=0;
    }
    const uint4* wb = wcf + w*512;
    uint4 h1 = wb[      lane], l1 = wb[ 64+lane];
    uint4 ht0= wb[128 + lane], lt0= wb[192+lane];
    uint4 ht1= wb[256 + lane], lt1= wb[320+lane];
    uint4 ht2= wb[384 + lane], lt2= wb[448+lane];
    int mrow = (lane>>4)*4;
    float bi0[4], bi1[4];
    #pragma unroll
    for(int r2=0;r2<4;++r2){
        int o = w*16 + mrow + r2;
        bi0[r2]=b1[o]; bi1[r2]=bt[o];
    }
    __syncthreads();
    float ls=0.f, lsq=0.f;
    int kb4 = (lane>>4)*4;
    for(int pt=0; pt<12; ++pt){
        int p = pt*16 + (lane&15);
        int node = p/24, t = p-node*24;
        int rc = (node*26 + t + 1)*XST;
        uint4 Bhm = *(const uint4*)&xh[rc - XST + kb4];
        uint4 Blm = *(const uint4*)&xl[rc - XST + kb4];
        uint4 Bhc = *(const uint4*)&xh[rc       + kb4];
        uint4 Blc = *(const uint4*)&xl[rc       + kb4];
        uint4 Bhp = *(const uint4*)&xh[rc + XST + kb4];
        uint4 Blp = *(const uint4*)&xl[rc + XST + kb4];
        f32x4 D0 = {bi0[0],bi0[1],bi0[2],bi0[3]};
        f32x4 D1 = {bi1[0],bi1[1],bi1[2],bi1[3]};
        D0 = MF(h1, Bhc, D0); D0 = MF(l1, Bhc, D0); D0 = MF(h1, Blc, D0);
        D1 = MF(ht0,Bhm, D1); D1 = MF(lt0,Bhm, D1); D1 = MF(ht0,Blm, D1);
        D1 = MF(ht1,Bhc, D1); D1 = MF(lt1,Bhc, D1); D1 = MF(ht1,Blc, D1);
        D1 = MF(ht2,Bhp, D1); D1 = MF(lt2,Bhp, D1); D1 = MF(ht2,Blp, D1);
        size_t gbase = ((size_t)(b*CO + w*16 + mrow)*NN + n0+node)*TT + t;
        #pragma unroll
        for(int r2=0;r2<4;++r2){
            xin[gbase + (size_t)r2*NT] = D0[r2];
            x1p[gbase + (size_t)r2*NT] = D1[r2];
            ls  += D1[r2];
            lsq += D1[r2]*D1[r2];
        }
    }
    red[tid]=ls; __syncthreads();
    for(int s=128;s>0;s>>=1){ if(tid<s) red[tid]+=red[tid+s]; __syncthreads(); }
    float tsum = red[0]; __syncthreads();
    red[tid]=lsq; __syncthreads();
    for(int s=128;s>0;s>>=1){ if(tid<s) red[tid]+=red[tid+s]; __syncthreads(); }
    if(tid==0){ atomicAdd(&stats[b], tsum); atomicAdd(&stats[8+b], red[0]); }
}

// ---- LN+leaky (fused) then h = stack(4*x1, adj^T x1); h stored packed bf16 ----
__global__ __launch_bounds__(512, 4) void k_hbuild(fp x1p, fp lng, fp lnb,
        const float* stats, const int* cnt, const int* idx, const float* val, unsigned* h){
    __shared__ float xs[NN*HSS];          // 57.3 KB
    int blk = blockIdx.x; int b = blk >> 6; int c = blk & 63;
    int tid = threadIdx.x;
    float mm = stats[b] / (float)LNCNT;
    float vv = fmaxf(stats[8+b] / (float)LNCNT - mm*mm, 0.f);
    float m = mm, inv = rsqrtf(vv + EPSL);
    fp src  = x1p + (size_t)(b*CO + c)*NT;
    fp gsrc = lng + (size_t)c*NT;
    fp bsrc = lnb + (size_t)c*NT;
    for(int i4=tid;i4<NT/4;i4+=512){
        int i = i4*4;
        int n = i/TT, t = i-n*TT;
        float4 s  = *(const float4*)(src + i);
        float4 g  = *(const float4*)(gsrc + i);
        float4 bb = *(const float4*)(bsrc + i);
        *(float4*)&xs[n*HSS + t] = make_float4(
            lk((s.x-m)*inv*g.x+bb.x), lk((s.y-m)*inv*g.y+bb.y),
            lk((s.z-m)*inv*g.z+bb.z), lk((s.w-m)*inv*g.w+bb.w));
    }
    int n = tid;
    int c0 = cnt[n];
    int cq = c0 > MAXNZ ? MAXNZ : c0;
    int4 j0 = *(const int4*)&idx[n*MAXNZ+0];   // prefetch (entries >= cq unused)
    int4 j1 = *(const int4*)&idx[n*MAXNZ+4];
    int4 j2 = *(const int4*)&idx[n*MAXNZ+8];
    float4 v0 = *(const float4*)&val[n*MAXNZ+0];
    float4 v1 = *(const float4*)&val[n*MAXNZ+4];
    float4 v2 = *(const float4*)&val[n*MAXNZ+8];
    __syncthreads();
    float acc[TT];
    #pragma unroll
    for(int l=0;l<TT;++l) acc[l]=0.f;
#define HB(J,U,V) if((J)<cq){ const float4* rp=(const float4*)&xs[(U)*HSS]; \
    _Pragma("unroll") for(int k=0;k<6;++k){ float4 wv=rp[k]; \
        acc[4*k]+=(V)*wv.x; acc[4*k+1]+=(V)*wv.y; acc[4*k+2]+=(V)*wv.z; acc[4*k+3]+=(V)*wv.w; } }
    HB(0,j0.x,v0.x) HB(1,j0.y,v0.y) HB(2,j0.z,v0.z) HB(3,j0.w,v0.w)
    HB(4,j1.x,v1.x) HB(5,j1.y,v1.y) HB(6,j1.z,v1.z) HB(7,j1.w,v1.w)
    HB(8,j2.x,v2.x) HB(9,j2.y,v2.y) HB(10,j2.z,v2.z) HB(11,j2.w,v2.w)
    for(int j=12;j<cq;++j){
        int u = idx[n*MAXNZ+j]; float v = val[n*MAXNZ+j];
        const float4* rp = (const float4*)&xs[u*HSS];
        #pragma unroll
        for(int k=0;k<6;++k){ float4 wv=rp[k];
            acc[4*k]+=v*wv.x; acc[4*k+1]+=v*wv.y; acc[4*k+2]+=v*wv.z; acc[4*k+3]+=v*wv.w; }
    }
    float t1[TT];
    const float4* sp = (const float4*)&xs[n*HSS];
    #pragma unroll
    for(int k=0;k<6;++k){
        float4 v = sp[k];
        t1[4*k]=v.x; t1[4*k+1]=v.y; t1[4*k+2]=v.z; t1[4*k+3]=v.w;
    }
    unsigned* h0 = h + (size_t)((b*CO+c)*2)*(NT/2);
    unsigned* h1 = h0 + NT/2;
    #pragma unroll
    for(int k=0;k<3;++k){
        *(uint4*)(h0 + n*12 + 4*k) = make_uint4(
            pk2(4.f*t1[8*k],  4.f*t1[8*k+1]), pk2(4.f*t1[8*k+2],4.f*t1[8*k+3]),
            pk2(4.f*t1[8*k+4],4.f*t1[8*k+5]), pk2(4.f*t1[8*k+6],4.f*t1[8*k+7]));
        *(uint4*)(h1 + n*12 + 4*k) = make_uint4(
            pk2(acc[8*k],  acc[8*k+1]), pk2(acc[8*k+2],acc[8*k+3]),
            pk2(acc[8*k+4],acc[8*k+5]), pk2(acc[8*k+6],acc[8*k+7]));
    }
}

// ======================= MFMA-based fused GraphSAGE x2 =======================
static __device__ __forceinline__ void acc8v(f32x2* t, uint4 q){
    t[0] += (f32x2){lo2f(q.x), hi2f(q.x)};
    t[1] += (f32x2){lo2f(q.y), hi2f(q.y)};
    t[2] += (f32x2){lo2f(q.z), hi2f(q.z)};
    t[3] += (f32x2){lo2f(q.w), hi2f(q.w)};
}

#define GBODY(u) { int ro=(u)*12; \
    uint4 q0=*(const uint4*)&hsb[ro]; \
    uint4 q1=*(const uint4*)&hsb[ro+4]; \
    uint4 q2=*(const uint4*)&hsb[ro+8]; \
    acc8v(t2v,q0); acc8v(t2v+4,q1); acc8v(t2v+8,q2); }
#define GSTEP(J,U) if((J)<cq) GBODY(U)

__global__ __launch_bounds__(512, 4) void k_sageF(unsigned* h, const uint4* wf,
        fp s0b, fp s1b, const int* cnt, const int* idx){
    __shared__ unsigned hsb[NN*12];       // 24 KB, the ONLY buffer
    int tid  = threadIdx.x;
    int lane = tid & 63;
    int wv   = tid >> 6;
    unsigned* base = h + (size_t)blockIdx.x*(NT/2);

    for(int i=tid;i<1536;i+=512) ((uint4*)hsb)[i] = ((const uint4*)base)[i];
    int n  = tid;              // gather: this thread owns node n
    int c0 = cnt[n];
    float di = 1.f / (float)(c0 < 1 ? 1 : c0);
    int cq = c0 > MAXNZ ? MAXNZ : c0;
    int4 i0 = *(const int4*)&idx[n*MAXNZ+0];   // prefetch (entries >= cq unused)
    int4 i1 = *(const int4*)&idx[n*MAXNZ+4];
    int4 i2 = *(const int4*)&idx[n*MAXNZ+8];
    __syncthreads();

    for(int layer=0; layer<2; ++layer){
        const uint4* wl = wf + layer*512;
        uint4 wsHiA = wl[      lane], wsLoA = wl[ 64+lane];
        uint4 wsHiB = wl[128 + lane], wsLoB = wl[192+lane];
        uint4 wnHiA = wl[256 + lane], wnLoA = wl[320+lane];
        uint4 wnHiB = wl[384 + lane], wnLoB = wl[448+lane];
        fp Bp = layer ? s1b : s0b;
        float biA[4], biB[4];
        #pragma unroll
        for(int r=0;r<4;++r){
            biA[r] = Bp[(lane>>4)*4 + r];
            int m2 = 16 + (lane>>4)*4 + r;
            biB[r] = (m2 < TT) ? Bp[m2] : 0.f;
        }

        // ---- phase 1: gather t2 (reads hsb); load B0 frags (own rows) ----
        f32x2 t2v[12];
        #pragma unroll
        for(int l=0;l<12;++l) t2v[l] = (f32x2){0.f,0.f};
        GSTEP(0,i0.x) GSTEP(1,i0.y) GSTEP(2,i0.z) GSTEP(3,i0.w)
        GSTEP(4,i1.x) GSTEP(5,i1.y) GSTEP(6,i1.z) GSTEP(7,i1.w)
        GSTEP(8,i2.x) GSTEP(9,i2.y) GSTEP(10,i2.z) GSTEP(11,i2.w)
        for(int j=12;j<cq;++j){ int u=idx[n*MAXNZ+j]; GBODY(u) }
        #pragma unroll
        for(int l=0;l<12;++l) t2v[l] *= di;

        uint4 b0[4];
        #pragma unroll
        for(int i=0;i<4;++i) b0[i]=make_uint4(0,0,0,0);
        if(lane < 48){
            #pragma unroll
            for(int i=0;i<4;++i){
                int nn_ = wv*64 + i*16 + (lane&15);
                b0[i] = *(const uint4*)&hsb[nn_*12 + ((lane>>4)<<2)];
            }
        }
        __syncthreads();   // ALL hsb reads (gather + B0, all waves) complete

        // ---- t2 pack -> own hsb row (input slab now dead) ----
        *(uint4*)&hsb[n*12  ] = make_uint4(
            pk2(t2v[0].x,t2v[0].y), pk2(t2v[1].x,t2v[1].y),
            pk2(t2v[2].x,t2v[2].y), pk2(t2v[3].x,t2v[3].y));
        *(uint4*)&hsb[n*12+4] = make_uint4(
            pk2(t2v[4].x,t2v[4].y), pk2(t2v[5].x,t2v[5].y),
            pk2(t2v[6].x,t2v[6].y), pk2(t2v[7].x,t2v[7].y));
        *(uint4*)&hsb[n*12+8] = make_uint4(
            pk2(t2v[8].x,t2v[8].y), pk2(t2v[9].x,t2v[9].y),
            pk2(t2v[10].x,t2v[10].y), pk2(t2v[11].x,t2v[11].y));
        __syncthreads();   // t2 rows visible

        // ---- phase 2: B1 frags (own rows), 32 MFMAs, pack, D -> own rows ----
        uint4 b1[4];
        #pragma unroll
        for(int i=0;i<4;++i) b1[i]=make_uint4(0,0,0,0);
        if(lane < 48){
            #pragma unroll
            for(int i=0;i<4;++i){
                int nn_ = wv*64 + i*16 + (lane&15);
                b1[i] = *(const uint4*)&hsb[nn_*12 + ((lane>>4)<<2)];
            }
        }
        uint2 pa[4], pb[4];
        #pragma unroll
        for(int i=0;i<4;++i){
            f32x4 Da = {biA[0],biA[1],biA[2],biA[3]};
            f32x4 Db = {biB[0],biB[1],biB[2],biB[3]};
            Da = MF(wsHiA, b0[i], Da);
            Da = MF(wsLoA, b0[i], Da);
            Da = MF(wnHiA, b1[i], Da);
            Da = MF(wnLoA, b1[i], Da);
            Db = MF(wsHiB, b0[i], Db);
            Db = MF(wsLoB, b0[i], Db);
            Db = MF(wnHiB, b1[i], Db);
            Db = MF(wnLoB, b1[i], Db);
            pa[i] = make_uint2(pk2(Da[0],Da[1]), pk2(Da[2],Da[3]));
            pb[i] = make_uint2(pk2(Db[0],Db[1]), pk2(Db[2],Db[3]));
        }
        __syncthreads();   // all B1 reads done before D overwrites rows
        #pragma unroll
        for(int i=0;i<4;++i){
            int nn_ = wv*64 + i*16 + (lane&15);
            int o = (lane>>4)*2;           // uints {0,2,4,6}: m = 2o..2o+3
            *(uint2*)&hsb[nn_*12 + o] = pa[i];
            if(lane < 32){                 // m = 16..23 -> uints {8,10}
                *(uint2*)&hsb[nn_*12 + 8 + (lane>>4)*2] = pb[i];
            }
        }
        __syncthreads();   // D visible for next layer's gather / writeback
    }
    for(int i=tid;i<1536;i+=512) ((uint4*)base)[i] = ((const uint4*)hsb)[i];
}

// ---- merged f1+f2: blocks [0,512) = f1 role, [512,1024) = f2 ----
#define F2S 25
__global__ __launch_bounds__(256) void k_f12(const unsigned* h, fp w1, fp w2,
        float* f1, float* f2){
    __shared__ float red[256*F2S];
    int tid = threadIdx.x;
    if(blockIdx.x < 512){
        // f1[b,l,n] = sum_c sg(gate)*lk(filt)*w1[c]
        if(tid < 192){
            int blk = blockIdx.x; int b = blk>>6; int n0 = (blk&63)*8;
            float acc = 0.f;
            const unsigned* fb = h + (size_t)b*CO*NT + n0*12;
            const unsigned* gb = fb + (size_t)CO*(NT/2);
            int e = tid;
            for(int c=0;c<CO;++c){
                float w = w1[c];
                unsigned f = fb[(size_t)c*(NT/2) + (e>>1)];
                unsigned g = gb[(size_t)c*(NT/2) + (e>>1)];
                float fv = (e&1) ? hi2f(f) : lo2f(f);
                float gv = (e&1) ? hi2f(g) : lo2f(g);
                acc += sg(gv)*lk(fv)*w;
            }
            int nl = e/TT, t = e%TT;
            f1[(b*TT+t)*NN + n0+nl] = acc;
        }
        return;
    }
    // f2[b,c,l] = sum_n sg(gate)*lk(filt)*w2[n]
    int blk = blockIdx.x - 512; int b = blk/CO; int c = blk%CO;
    float acc[TT];
    #pragma unroll
    for(int l=0;l<TT;++l) acc[l]=0.f;
    const unsigned* fb = h + (size_t)b*CO*NT + (size_t)c*(NT/2);
    const unsigned* gb = fb + (size_t)CO*(NT/2);
    for(int n=tid;n<NN;n+=256){
        float w = w2[n];
        #pragma unroll
        for(int k=0;k<3;++k){
            uint4 f = *(const uint4*)(fb + n*12 + 4*k);
            uint4 g = *(const uint4*)(gb + n*12 + 4*k);
            acc[8*k  ] += sg(lo2f(g.x))*lk(lo2f(f.x))*w;
            acc[8*k+1] += sg(hi2f(g.x))*lk(hi2f(f.x))*w;
            acc[8*k+2] += sg(lo2f(g.y))*lk(lo2f(f.y))*w;
            acc[8*k+3] += sg(hi2f(g.y))*lk(hi2f(f.y))*w;
            acc[8*k+4] += sg(lo2f(g.z))*lk(lo2f(f.z))*w;
            acc[8*k+5] += sg(hi2f(g.z))*lk(hi2f(f.z))*w;
            acc[8*k+6] += sg(lo2f(g.w))*lk(lo2f(f.w))*w;
            acc[8*k+7] += sg(hi2f(g.w))*lk(hi2f(f.w))*w;
        }
    }
    #pragma unroll
    for(int l=0;l<TT;++l) red[tid*F2S+l]=acc[l];
    __syncthreads();
    for(int s=128;s>0;s>>=1){
        if(tid<s){
            #pragma unroll
            for(int l=0;l<TT;++l) red[tid*F2S+l]+=red[(tid+s)*F2S+l];
        }
        __syncthreads();
    }
    if(tid<TT) f2[(b*CO+c)*TT+tid] = red[tid];
}

// ---- merged dilated convs: blocks 0..31 = conv over n on f1; 32..39 = over l on f2 ----
__global__ __launch_bounds__(256) void k_convf(fp f1, fp wd1, float* f1c,
        fp f2, fp wd2, float* f2c){
    __shared__ float sm[9856];            // union: f1 path 4272 fl, f2 path 9856 fl
    int tid=threadIdx.x;
    if(blockIdx.x < 32){
        float* fs  = sm;                  // [TT][130]
        float* w0  = sm + 3120;
        float* w1a = sm + 3696;
        int bid = blockIdx.x; int b = bid>>2; int n0 = (bid&3)*128;
        for(int i=tid;i<TT*130;i+=256){
            int l=i/130, col=i%130; int n = n0+col-1;
            fs[l*130+col] = (n>=0 && n<NN) ? f1[(b*TT+l)*NN+n] : 0.f;
        }
        for(int i=tid;i<TT*TT;i+=256){ w0[i]=wd1[i*2]; w1a[i]=wd1[i*2+1]; }
        __syncthreads();
        for(int j=tid;j<TT*128;j+=256){
            int o=j>>7, nn=j&127;
            float acc=0.f;
            #pragma unroll
            for(int i=0;i<TT;++i) acc += fs[i*130+nn]*w0[o*TT+i] + fs[i*130+nn+2]*w1a[o*TT+i];
            f1c[(b*TT+o)*NN+n0+nn]=acc;
        }
        return;
    }
    float* fs  = sm;                      // [CO][TT+2]
    float* w0  = sm + 1664;
    float* w1a = sm + 5760;
    int b = blockIdx.x - 32;
    for(int i=tid;i<CO*TT;i+=256){ int c=i/TT,l=i%TT; fs[c*26+l+1]=f2[(b*CO+c)*TT+l]; }
    for(int c=tid;c<CO;c+=256){ fs[c*26]=0.f; fs[c*26+TT+1]=0.f; }
    for(int i=tid;i<CO*CO;i+=256){ w0[i]=wd2[i*2]; w1a[i]=wd2[i*2+1]; }
    __syncthreads();
    for(int j=tid;j<CO*TT;j+=256){
        int o=j/TT, l=j%TT;
        float acc=0.f;
        for(int i=0;i<CO;++i) acc += fs[i*26+l]*w0[o*CO+i] + fs[i*26+l+2]*w1a[o*CO+i];
        f2c[(b*CO+o)*TT+l]=acc;
    }
}

// ---------------- g1[b,l,c] = sum_n f1c[b,l,n]*tW[n,c] ----------------
__global__ __launch_bounds__(384) void k_g1(fp f1c, fp tW, float* g1){
    __shared__ float fs[6*NN];
    int blk=blockIdx.x; int b=blk>>2; int part=blk&3;
    int tid=threadIdx.x;
    for(int i=tid;i<6*NN;i+=384) fs[i]=f1c[b*TT*NN + part*6*NN + i];
    __syncthreads();
    int c = tid & 63; int r = tid >> 6;   // r = 0..5
    float acc=0.f;
    for(int n=0;n<NN;++n) acc += fs[r*NN + n]*tW[n*CO + c];
    g1[(b*TT + part*6 + r)*CO + c] = acc;
}

// -------- logits: A = sig matmul (18 blk); BC = t_v matmul + BN + softmax (1 blk) --
__global__ __launch_bounds__(256) void k_lgA(fp g1, fp f2c, fp tbias, float* sig){
    int j = blockIdx.x*256 + threadIdx.x;
    int b=j/(TT*TT); int r=j%(TT*TT); int l=r/TT; int q=r%TT;
    float acc = tbias[l*TT+q];
    fp gg = g1 + (b*TT+l)*CO;
    fp ff = f2c + b*CO*TT + q;
    for(int c=0;c<CO;++c) acc += gg[c]*ff[c*TT];
    sig[j] = sg(acc);
}
__global__ __launch_bounds__(256) void k_lgBC(fp tv, const float* sig,
        fp bng, fp bnb, float* coefs, float* tco){
    __shared__ float lg2[B_*TT*TT];       // 18.4 KB
    __shared__ float muq[TT], scq[TT], shq[TT];
    int tid=threadIdx.x;
    for(int j=tid;j<B_*TT*TT;j+=256){
        int b=j/(TT*TT); int r=j%(TT*TT); int l=r/TT; int q=r%TT;
        float acc=0.f;
        for(int k=0;k<TT;++k) acc += tv[l*TT+k]*sig[(b*TT+k)*TT+q];
        lg2[j]=acc;
    }
    __syncthreads();
    if(tid<TT){
        int q=tid;
        float s=0.f;
        for(int b=0;b<B_;++b) for(int l=0;l<TT;++l) s += lg2[(b*TT+l)*TT+q];
        float mu = s/192.f;
        float v=0.f;
        for(int b=0;b<B_;++b) for(int l=0;l<TT;++l){ float d = lg2[(b*TT+l)*TT+q]-mu; v += d*d; }
        v = fmaxf(v/192.f, 0.f);
        muq[q]=mu; scq[q]=rsqrtf(v+EPSL)*bng[q]; shq[q]=bnb[q];
    }
    __syncthreads();
    if(tid<192){
        int b=tid/TT, l=tid%TT;
        int base = (l<12)?0:12;
        float z[12];
        float mx=-1e30f;
        #pragma unroll
        for(int r=0;r<12;++r){
            int q=base+r;
            float zv=(lg2[(b*TT+l)*TT+q]-muq[q])*scq[q]+shq[q];
            z[r]=zv; mx = fmaxf(mx,zv);
        }
        float s=0.f;
        #pragma unroll
        for(int r=0;r<12;++r){ z[r]=expf(z[r]-mx); s+=z[r]; }
        float is=1.f/s;
        for(int q=0;q<TT;++q){
            float cf = (q>=base && q<base+12) ? z[q-base]*is : 0.f;
            coefs[(b*TT+l)*TT+q]=cf;
            tco[(b*TT+q)*TT+l]=cf;
        }
    }
}

// ---- x1new = xg @ coefs^T ; y = leaky(x1new)+x_input ; LN stats ----
// (round-11 verified form: 1024 blocks, 1 node/thread, float4 cf reads)
__global__ __launch_bounds__(256, 4) void k_apply(const unsigned* h, fp xin, fp coefs,
        float* y, float* stats){
    __shared__ __attribute__((aligned(16))) float cf[TT*TT];
    __shared__ float red[256];
    int blk=blockIdx.x; int b=blk>>7; int c=(blk>>1)&63; int half=blk&1;
    int tid=threadIdx.x;
    for(int i=tid;i<TT*TT;i+=256) cf[i]=coefs[b*TT*TT+i];
    __syncthreads();
    int n = half*256 + tid;
    const unsigned* fb = h + (size_t)b*CO*NT + (size_t)c*(NT/2) + n*12;
    const unsigned* gb = fb + (size_t)CO*(NT/2);
    fp xrow = xin + (size_t)(b*CO+c)*NT + n*TT;
    float* yrow = y + (size_t)(b*CO+c)*NT + n*TT;
    float row[TT];
    #pragma unroll
    for(int k=0;k<3;++k){
        uint4 f = *(const uint4*)(fb + 4*k);
        uint4 g = *(const uint4*)(gb + 4*k);
        row[8*k  ] = sg(lo2f(g.x))*lk(lo2f(f.x));
        row[8*k+1] = sg(hi2f(g.x))*lk(hi2f(f.x));
        row[8*k+2] = sg(lo2f(g.y))*lk(lo2f(f.y));
        row[8*k+3] = sg(hi2f(g.y))*lk(hi2f(f.y));
        row[8*k+4] = sg(lo2f(g.z))*lk(lo2f(f.z));
        row[8*k+5] = sg(hi2f(g.z))*lk(hi2f(f.z));
        row[8*k+6] = sg(lo2f(g.w))*lk(lo2f(f.w));
        row[8*k+7] = sg(hi2f(g.w))*lk(hi2f(f.w));
    }
    float ls=0.f, lsq=0.f;
    #pragma unroll
    for(int k=0;k<6;++k){
        float4 u = *(const float4*)(xrow + 4*k);
        float a[4];
        #pragma unroll
        for(int j=0;j<4;++j){
            const float4* crow = (const float4*)&cf[(4*k+j)*TT];
            float acc=0.f;
            #pragma unroll
            for(int kk=0;kk<6;++kk){
                float4 cv = crow[kk];
                acc += row[4*kk  ]*cv.x;
                acc += row[4*kk+1]*cv.y;
                acc += row[4*kk+2]*cv.z;
                acc += row[4*kk+3]*cv.w;
            }
            a[j]=acc;
        }
        float y0 = lk(a[0])+u.x, y1 = lk(a[1])+u.y, y2 = lk(a[2])+u.z, y3 = lk(a[3])+u.w;
        *(float4*)(yrow + 4*k) = make_float4(y0,y1,y2,y3);
        ls  += y0+y1+y2+y3;
        lsq += y0*y0+y1*y1+y2*y2+y3*y3;
    }
    red[tid]=ls; __syncthreads();
    for(int s=128;s>0;s>>=1){ if(tid<s) red[tid]+=red[tid+s]; __syncthreads(); }
    float t0=red[0]; __syncthreads();
    red[tid]=lsq; __syncthreads();
    for(int s=128;s>0;s>>=1){ if(tid<s) red[tid]+=red[tid+s]; __syncthreads(); }
    if(tid==0){ atomicAdd(&stats[32+b], t0); atomicAdd(&stats[40+b], red[0]); }
}

// ---------------- final LN apply; stats finalize inlined ----------------
__global__ void k_final(fp y, fp lng, fp lnb, const float* stats, float* out){
    float mb[8], sb[8];
    #pragma unroll
    for(int b=0;b<8;++b){
        float mm = stats[32+b] / (float)LNCNT;
        float vv = fmaxf(stats[40+b] / (float)LNCNT - mm*mm, 0.f);
        mb[b]=mm; sb[b]=rsqrtf(vv + EPSL);
    }
    int tot = B_*CO*NT;
    for(int i = blockIdx.x*blockDim.x + threadIdx.x; i<tot; i+=gridDim.x*blockDim.x){
        int b = i/LNCNT; int r = i%LNCNT;
        out[i] = (y[i]-mb[b])*sb[b]*lng[r]+lnb[r];
    }
}

extern "C" void kernel_launch(void* const* d_in, const int* in_sizes, int n_in,
                              void* d_out, int out_size, void* d_ws, size_t ws_size,
                              hipStream_t stream){
    fp x    = (fp)d_in[0];
    fp adj  = (fp)d_in[1];
    fp w1   = (fp)d_in[2];
    fp b1   = (fp)d_in[3];
    fp wt   = (fp)d_in[4];
    fp bt   = (fp)d_in[5];
    fp lng  = (fp)d_in[6];
    fp lnb  = (fp)d_in[7];
    fp s0ws = (fp)d_in[8];
    fp s0wn = (fp)d_in[9];
    fp s0b  = (fp)d_in[10];
    fp s1ws = (fp)d_in[11];
    fp s1wn = (fp)d_in[12];
    fp s1b  = (fp)d_in[13];
    fp tw1  = (fp)d_in[14];
    fp tw2  = (fp)d_in[15];
    fp twd1 = (fp)d_in[16];
    fp twd2 = (fp)d_in[17];
    fp tW   = (fp)d_in[18];
    fp tbias= (fp)d_in[19];
    fp tv   = (fp)d_in[20];
    fp bng  = (fp)d_in[21];
    fp bnb  = (fp)d_in[22];

    float* W = (float*)d_ws;            // stats [0..63]
    int*   CNTp = (int*)(W+256);        // 512 ints (zeroed each launch)
    int*   IDXp = (int*)(W+1280);
    float* VALp = W+34048;
    float* F1   = W+66816;
    float* F1C  = W+165120;
    float* F2   = W+263424;
    float* F2C  = W+275712;
    float* G1   = W+288000;
    float* CF   = W+300288;
    float* XIN  = W+304896;
    float* X1   = W+6596352;
    float* SIG  = W+6596352;            // reuse X1 head (dead after hbuild)
    uint4* WFq  = (uint4*)(W+12887808); // sage weight frags: 1024 uint4 = 16KB
    uint4* WCF  = (uint4*)(W+12891904); // conv weight frags: 2048 uint4 = 32KB
    unsigned* HA = (unsigned*)(W+19179264);   // packed bf16 h: 6291456 uints
    float* Y    = W+31762176;           // ends 38053632 floats = 152.2 MB
    float* LG2  = SIG + 4608;

    float* oout   = (float*)d_out;
    float* o_adj  = oout + 6291456;
    float* o_tc   = oout + 6291456 + 262144;

    hipMemsetAsync(W, 0, 768*sizeof(float), stream);   // stats + cnt
    k_cscw<<<1025,256,0,stream>>>(adj, CNTp, IDXp, VALp, o_adj,
                                  s0ws, s0wn, s1ws, s1wn, WFq, w1, wt, WCF);
    k_conv<<<512,256,0,stream>>>(x, WCF, b1, bt, XIN, X1, W);
    k_hbuild<<<512,512,0,stream>>>(X1, lng, lnb, W, CNTp, IDXp, VALp, HA);
    k_sageF<<<1024,512,0,stream>>>(HA, WFq, s0b, s1b, CNTp, IDXp);
    k_f12<<<1024,256,0,stream>>>(HA, tw1, tw2, F1, F2);
    k_convf<<<40,256,0,stream>>>(F1, twd1, F1C, F2, twd2, F2C);
    k_g1<<<32,384,0,stream>>>(F1C, tW, G1);
    k_lgA<<<18,256,0,stream>>>(G1, F2C, tbias, SIG);
    k_lgBC<<<1,256,0,stream>>>(tv, SIG, bng, bnb, CF, o_tc);
    k_apply<<<1024,256,0,stream>>>(HA, XIN, CF, Y, W);
    k_final<<<2048,256,0,stream>>>(Y, lng, lnb, W, oout);
}

// Round 14
// 346.133 us; speedup vs baseline: 1.1110x; 1.0211x over previous
//
#include <hip/hip_runtime.h>
#include <hip/hip_bf16.h>
#include <math.h>

#define B_    8
#define CIN   32
#define CO    64
#define NN    512
#define TT    24
#define NT    (NN*TT)        /* 12288 */
#define LNCNT (CO*NT)        /* 786432 */
#define EPSL  1e-5f
#define MAXNZ 64
#define HSS   28             /* fp32 LDS row stride (hbuild) */

typedef const float* fp;
static __device__ __forceinline__ float lk(float x){ return x > 0.f ? x : 0.01f*x; }
static __device__ __forceinline__ float sg(float x){
    if(x >= 0.f){ float e = expf(-x); return 1.f/(1.f+e); }
    float e = expf(x); return e/(1.f+e);
}
// bf16 pair pack/unpack (lo = even element, hi = odd element)
static __device__ __forceinline__ unsigned pk2(float a, float b){
    __hip_bfloat16 x = __float2bfloat16(a), y = __float2bfloat16(b);
    unsigned lo = *(unsigned short*)&x, hi = *(unsigned short*)&y;
    return lo | (hi<<16);
}
static __device__ __forceinline__ float lo2f(unsigned u){ return __uint_as_float(u<<16); }
static __device__ __forceinline__ float hi2f(unsigned u){ return __uint_as_float(u & 0xffff0000u); }

// load 8 weights w[m][kb..kb+7] (T=24 bounds -> 0 pad), split hi/lo bf16 frags
static __device__ __forceinline__ void ldw_split(fp w, int m, int kb, uint4* hi, uint4* lo){
    float vh[8], vl[8];
    #pragma unroll
    for(int j=0;j<8;++j){
        float v = (m < TT && (kb+j) < TT) ? w[m*TT + kb + j] : 0.f;
        __hip_bfloat16 hb = __float2bfloat16(v);
        float hf = __bfloat162float(hb);
        vh[j] = hf;
        vl[j] = v - hf;
    }
    *hi = make_uint4(pk2(vh[0],vh[1]),pk2(vh[2],vh[3]),pk2(vh[4],vh[5]),pk2(vh[6],vh[7]));
    *lo = make_uint4(pk2(vl[0],vl[1]),pk2(vl[2],vl[3]),pk2(vl[4],vl[5]),pk2(vl[6],vl[7]));
}

// ---- merged CSC build (blocks 0..1023) + weight frag prep (block 1024) ----
// NOTE (round 12 lesson): NO cooperative launches in this harness.
__global__ __launch_bounds__(256) void k_cscw(fp adj, int* cnt, int* idx, float* val,
        float* o_adj, fp s0ws, fp s0wn, fp s1ws, fp s1wn, uint4* wf,
        fp w1, fp wt, uint4* wcf){
    if(blockIdx.x < 1024){
        int e = blockIdx.x*256 + threadIdx.x;   // 0 .. NN*NN-1 exactly
        float a = adj[e];
        o_adj[e] = a;                           // replaces the D2D memcpy launch
        if(a != 0.f){
            int u = e >> 9, q = e & 511;
            int slot = atomicAdd(&cnt[q], 1);
            if(slot < MAXNZ){ idx[q*MAXNZ+slot] = u; val[q*MAXNZ+slot] = a; }
        }
        return;
    }
    int t = threadIdx.x;
    int lane = t & 63, g = t >> 6;
    {   // sage weights
        int M = g >> 1, H = g & 1;
        int m  = H*16 + (lane&15);
        int kb = (lane>>4)*8;
        for(int L=0; L<2; ++L){
            fp w = L ? (M ? s1wn : s1ws) : (M ? s0wn : s0ws);
            uint4 hi, lo;
            ldw_split(w, m, kb, &hi, &lo);
            wf[L*512 + g*128 +      lane] = hi;
            wf[L*512 + g*128 + 64 + lane] = lo;
        }
    }
    {   // conv weights
        int kb = (lane>>4)*8;
        for(int ot=0; ot<4; ++ot){
            int m = ot*16 + (lane&15);
            float vh[8], vl[8];
            #pragma unroll
            for(int j=0;j<8;++j){
                int c = kb+j;
                float v = (g==0) ? w1[m*CIN+c] : wt[(m*CIN+c)*3 + (g-1)];
                __hip_bfloat16 hb = __float2bfloat16(v);
                float hf = __bfloat162float(hb);
                vh[j]=hf; vl[j]=v-hf;
            }
            wcf[ot*512 + g*128 +      lane] = make_uint4(
                pk2(vh[0],vh[1]),pk2(vh[2],vh[3]),pk2(vh[4],vh[5]),pk2(vh[6],vh[7]));
            wcf[ot*512 + g*128 + 64 + lane] = make_uint4(
                pk2(vl[0],vl[1]),pk2(vl[2],vl[3]),pk2(vl[4],vl[5]),pk2(vl[6],vl[7]));
        }
    }
}

// ---- degree-sorted node permutation (round 14): counting sort, 1 block ----
// Waves in the gather kernels pay max(deg) over 64 lanes (~19 for binomial
// mean 10.2); sorting nodes by degree makes per-wave max ~= avg (~10.5).
// Any bijection is valid: per-node arithmetic is independent & unchanged.
__global__ __launch_bounds__(512) void k_perm(const int* cnt, int* perm){
    __shared__ int hist[65];
    __shared__ int base[65];
    int tid = threadIdx.x;
    if(tid < 65) hist[tid] = 0;
    __syncthreads();
    int c0 = cnt[tid];
    int c = c0 < 0 ? 0 : (c0 > 64 ? 64 : c0);
    atomicAdd(&hist[c], 1);
    __syncthreads();
    if(tid == 0){
        int s = 0;
        for(int i=0;i<65;++i){ base[i] = s; s += hist[i]; }
    }
    __syncthreads();
    int pos = atomicAdd(&base[c], 1);
    perm[pos] = tid;
}

typedef __attribute__((ext_vector_type(8))) short bf16x8;
typedef __attribute__((ext_vector_type(4))) float f32x4;
typedef __attribute__((ext_vector_type(2))) float f32x2;

static __device__ __forceinline__ f32x4 MF(uint4 a, uint4 b, f32x4 c){
    union { uint4 u; bf16x8 v; } A, Bv; A.u = a; Bv.u = b;
    return __builtin_amdgcn_mfma_f32_16x16x32_bf16(A.v, Bv.v, c, 0, 0, 0);
}

// ======================= MFMA conv1 + temporal conv + LN stats ================
#define XST 20
__global__ __launch_bounds__(256, 4) void k_conv(fp x, const uint4* wcf, fp b1, fp bt,
        float* xin, float* x1p, float* stats){
    __shared__ __attribute__((aligned(16))) unsigned xh[208*XST];
    __shared__ __attribute__((aligned(16))) unsigned xl[208*XST];
    __shared__ float red[256];
    int bid = blockIdx.x; int b = bid>>6; int n0 = (bid&63)*8;
    int tid = threadIdx.x; int lane = tid&63; int w = tid>>6;
    for(int i=tid;i<3072;i+=256){
        int cp = i/192; int r = i-cp*192; int node = r/24; int t = r-node*24;
        const float* xp = x + ((size_t)(b*CIN + 2*cp)*NN + n0+node)*TT + t;
        float a = xp[0], b2 = xp[NT];
        __hip_bfloat16 ab = __float2bfloat16(a), bb = __float2bfloat16(b2);
        float ah = __bfloat162float(ab), bh = __bfloat162float(bb);
        int row = node*26 + t + 1;
        xh[row*XST+cp] = pk2(ah, bh);
        xl[row*XST+cp] = pk2(a-ah, b2-bh);
    }
    {   // zero guard rows (t=-1 and t=24 per node): 8*2*16 = 256 slots
        int node = tid>>5; int which = (tid>>4)&1; int j = tid&15;
        int row = node*26 + which*25;
        xh[row*XST+j]=0; xl[row*XST+j]=0;
    }
    const uint4* wb = wcf + w*512;
    uint4 h1 = wb[      lane], l1 = wb[ 64+lane];
    uint4 ht0= wb[128 + lane], lt0= wb[192+lane];
    uint4 ht1= wb[256 + lane], lt1= wb[320+lane];
    uint4 ht2= wb[384 + lane], lt2= wb[448+lane];
    int mrow = (lane>>4)*4;
    float bi0[4], bi1[4];
    #pragma unroll
    for(int r2=0;r2<4;++r2){
        int o = w*16 + mrow + r2;
        bi0[r2]=b1[o]; bi1[r2]=bt[o];
    }
    __syncthreads();
    float ls=0.f, lsq=0.f;
    int kb4 = (lane>>4)*4;
    for(int pt=0; pt<12; ++pt){
        int p = pt*16 + (lane&15);
        int node = p/24, t = p-node*24;
        int rc = (node*26 + t + 1)*XST;
        uint4 Bhm = *(const uint4*)&xh[rc - XST + kb4];
        uint4 Blm = *(const uint4*)&xl[rc - XST + kb4];
        uint4 Bhc = *(const uint4*)&xh[rc       + kb4];
        uint4 Blc = *(const uint4*)&xl[rc       + kb4];
        uint4 Bhp = *(const uint4*)&xh[rc + XST + kb4];
        uint4 Blp = *(const uint4*)&xl[rc + XST + kb4];
        f32x4 D0 = {bi0[0],bi0[1],bi0[2],bi0[3]};
        f32x4 D1 = {bi1[0],bi1[1],bi1[2],bi1[3]};
        D0 = MF(h1, Bhc, D0); D0 = MF(l1, Bhc, D0); D0 = MF(h1, Blc, D0);
        D1 = MF(ht0,Bhm, D1); D1 = MF(lt0,Bhm, D1); D1 = MF(ht0,Blm, D1);
        D1 = MF(ht1,Bhc, D1); D1 = MF(lt1,Bhc, D1); D1 = MF(ht1,Blc, D1);
        D1 = MF(ht2,Bhp, D1); D1 = MF(lt2,Bhp, D1); D1 = MF(ht2,Blp, D1);
        size_t gbase = ((size_t)(b*CO + w*16 + mrow)*NN + n0+node)*TT + t;
        #pragma unroll
        for(int r2=0;r2<4;++r2){
            xin[gbase + (size_t)r2*NT] = D0[r2];
            x1p[gbase + (size_t)r2*NT] = D1[r2];
            ls  += D1[r2];
            lsq += D1[r2]*D1[r2];
        }
    }
    red[tid]=ls; __syncthreads();
    for(int s=128;s>0;s>>=1){ if(tid<s) red[tid]+=red[tid+s]; __syncthreads(); }
    float tsum = red[0]; __syncthreads();
    red[tid]=lsq; __syncthreads();
    for(int s=128;s>0;s>>=1){ if(tid<s) red[tid]+=red[tid+s]; __syncthreads(); }
    if(tid==0){ atomicAdd(&stats[b], tsum); atomicAdd(&stats[8+b], red[0]); }
}

// ---- LN+leaky (fused) then h = stack(4*x1, adj^T x1); h stored packed bf16 ----
// Round 14: node handled by thread = perm[tid] (degree-balanced waves).
__global__ __launch_bounds__(512, 4) void k_hbuild(fp x1p, fp lng, fp lnb,
        const float* stats, const int* cnt, const int* idx, const float* val,
        const int* perm, unsigned* h){
    __shared__ float xs[NN*HSS];          // 57.3 KB
    int blk = blockIdx.x; int b = blk >> 6; int c = blk & 63;
    int tid = threadIdx.x;
    float mm = stats[b] / (float)LNCNT;
    float vv = fmaxf(stats[8+b] / (float)LNCNT - mm*mm, 0.f);
    float m = mm, inv = rsqrtf(vv + EPSL);
    fp src  = x1p + (size_t)(b*CO + c)*NT;
    fp gsrc = lng + (size_t)c*NT;
    fp bsrc = lnb + (size_t)c*NT;
    for(int i4=tid;i4<NT/4;i4+=512){
        int i = i4*4;
        int n = i/TT, t = i-n*TT;
        float4 s  = *(const float4*)(src + i);
        float4 g  = *(const float4*)(gsrc + i);
        float4 bb = *(const float4*)(bsrc + i);
        *(float4*)&xs[n*HSS + t] = make_float4(
            lk((s.x-m)*inv*g.x+bb.x), lk((s.y-m)*inv*g.y+bb.y),
            lk((s.z-m)*inv*g.z+bb.z), lk((s.w-m)*inv*g.w+bb.w));
    }
    int n = perm[tid];
    int c0 = cnt[n];
    int cq = c0 > MAXNZ ? MAXNZ : c0;
    int4 j0 = *(const int4*)&idx[n*MAXNZ+0];   // prefetch (entries >= cq unused)
    int4 j1 = *(const int4*)&idx[n*MAXNZ+4];
    int4 j2 = *(const int4*)&idx[n*MAXNZ+8];
    float4 v0 = *(const float4*)&val[n*MAXNZ+0];
    float4 v1 = *(const float4*)&val[n*MAXNZ+4];
    float4 v2 = *(const float4*)&val[n*MAXNZ+8];
    __syncthreads();
    float acc[TT];
    #pragma unroll
    for(int l=0;l<TT;++l) acc[l]=0.f;
#define HB(J,U,V) if((J)<cq){ const float4* rp=(const float4*)&xs[(U)*HSS]; \
    _Pragma("unroll") for(int k=0;k<6;++k){ float4 wv=rp[k]; \
        acc[4*k]+=(V)*wv.x; acc[4*k+1]+=(V)*wv.y; acc[4*k+2]+=(V)*wv.z; acc[4*k+3]+=(V)*wv.w; } }
    HB(0,j0.x,v0.x) HB(1,j0.y,v0.y) HB(2,j0.z,v0.z) HB(3,j0.w,v0.w)
    HB(4,j1.x,v1.x) HB(5,j1.y,v1.y) HB(6,j1.z,v1.z) HB(7,j1.w,v1.w)
    HB(8,j2.x,v2.x) HB(9,j2.y,v2.y) HB(10,j2.z,v2.z) HB(11,j2.w,v2.w)
    for(int j=12;j<cq;++j){
        int u = idx[n*MAXNZ+j]; float v = val[n*MAXNZ+j];
        const float4* rp = (const float4*)&xs[u*HSS];
        #pragma unroll
        for(int k=0;k<6;++k){ float4 wv=rp[k];
            acc[4*k]+=v*wv.x; acc[4*k+1]+=v*wv.y; acc[4*k+2]+=v*wv.z; acc[4*k+3]+=v*wv.w; }
    }
    float t1[TT];
    const float4* sp = (const float4*)&xs[n*HSS];
    #pragma unroll
    for(int k=0;k<6;++k){
        float4 v = sp[k];
        t1[4*k]=v.x; t1[4*k+1]=v.y; t1[4*k+2]=v.z; t1[4*k+3]=v.w;
    }
    unsigned* h0 = h + (size_t)((b*CO+c)*2)*(NT/2);
    unsigned* h1 = h0 + NT/2;
    #pragma unroll
    for(int k=0;k<3;++k){
        *(uint4*)(h0 + n*12 + 4*k) = make_uint4(
            pk2(4.f*t1[8*k],  4.f*t1[8*k+1]), pk2(4.f*t1[8*k+2],4.f*t1[8*k+3]),
            pk2(4.f*t1[8*k+4],4.f*t1[8*k+5]), pk2(4.f*t1[8*k+6],4.f*t1[8*k+7]));
        *(uint4*)(h1 + n*12 + 4*k) = make_uint4(
            pk2(acc[8*k],  acc[8*k+1]), pk2(acc[8*k+2],acc[8*k+3]),
            pk2(acc[8*k+4],acc[8*k+5]), pk2(acc[8*k+6],acc[8*k+7]));
    }
}

// ======================= MFMA-based fused GraphSAGE x2 =======================
static __device__ __forceinline__ void acc8v(f32x2* t, uint4 q){
    t[0] += (f32x2){lo2f(q.x), hi2f(q.x)};
    t[1] += (f32x2){lo2f(q.y), hi2f(q.y)};
    t[2] += (f32x2){lo2f(q.z), hi2f(q.z)};
    t[3] += (f32x2){lo2f(q.w), hi2f(q.w)};
}

#define GBODY(u) { int ro=(u)*12; \
    uint4 q0=*(const uint4*)&hsb[ro]; \
    uint4 q1=*(const uint4*)&hsb[ro+4]; \
    uint4 q2=*(const uint4*)&hsb[ro+8]; \
    acc8v(t2v,q0); acc8v(t2v+4,q1); acc8v(t2v+8,q2); }
#define GSTEP(J,U) if((J)<cq) GBODY(U)

__global__ __launch_bounds__(512, 4) void k_sageF(unsigned* h, const uint4* wf,
        fp s0b, fp s1b, const int* cnt, const int* idx, const int* perm){
    __shared__ unsigned hsb[NN*12];       // 24 KB, the ONLY buffer
    int tid  = threadIdx.x;
    int lane = tid & 63;
    int wv   = tid >> 6;
    unsigned* base = h + (size_t)blockIdx.x*(NT/2);

    for(int i=tid;i<1536;i+=512) ((uint4*)hsb)[i] = ((const uint4*)base)[i];
    int n  = perm[tid];        // gather: this thread owns node n (deg-balanced)
    int c0 = cnt[n];
    float di = 1.f / (float)(c0 < 1 ? 1 : c0);
    int cq = c0 > MAXNZ ? MAXNZ : c0;
    int4 i0 = *(const int4*)&idx[n*MAXNZ+0];   // prefetch (entries >= cq unused)
    int4 i1 = *(const int4*)&idx[n*MAXNZ+4];
    int4 i2 = *(const int4*)&idx[n*MAXNZ+8];
    __syncthreads();

    for(int layer=0; layer<2; ++layer){
        const uint4* wl = wf + layer*512;
        uint4 wsHiA = wl[      lane], wsLoA = wl[ 64+lane];
        uint4 wsHiB = wl[128 + lane], wsLoB = wl[192+lane];
        uint4 wnHiA = wl[256 + lane], wnLoA = wl[320+lane];
        uint4 wnHiB = wl[384 + lane], wnLoB = wl[448+lane];
        fp Bp = layer ? s1b : s0b;
        float biA[4], biB[4];
        #pragma unroll
        for(int r=0;r<4;++r){
            biA[r] = Bp[(lane>>4)*4 + r];
            int m2 = 16 + (lane>>4)*4 + r;
            biB[r] = (m2 < TT) ? Bp[m2] : 0.f;
        }

        // ---- phase 1: gather t2 (reads hsb); load B0 frags (own rows) ----
        f32x2 t2v[12];
        #pragma unroll
        for(int l=0;l<12;++l) t2v[l] = (f32x2){0.f,0.f};
        GSTEP(0,i0.x) GSTEP(1,i0.y) GSTEP(2,i0.z) GSTEP(3,i0.w)
        GSTEP(4,i1.x) GSTEP(5,i1.y) GSTEP(6,i1.z) GSTEP(7,i1.w)
        GSTEP(8,i2.x) GSTEP(9,i2.y) GSTEP(10,i2.z) GSTEP(11,i2.w)
        for(int j=12;j<cq;++j){ int u=idx[n*MAXNZ+j]; GBODY(u) }
        #pragma unroll
        for(int l=0;l<12;++l) t2v[l] *= di;

        uint4 b0[4];
        #pragma unroll
        for(int i=0;i<4;++i) b0[i]=make_uint4(0,0,0,0);
        if(lane < 48){
            #pragma unroll
            for(int i=0;i<4;++i){
                int nn_ = wv*64 + i*16 + (lane&15);
                b0[i] = *(const uint4*)&hsb[nn_*12 + ((lane>>4)<<2)];
            }
        }
        __syncthreads();   // ALL hsb reads (gather + B0, all waves) complete

        // ---- t2 pack -> own hsb row (input slab now dead) ----
        *(uint4*)&hsb[n*12  ] = make_uint4(
            pk2(t2v[0].x,t2v[0].y), pk2(t2v[1].x,t2v[1].y),
            pk2(t2v[2].x,t2v[2].y), pk2(t2v[3].x,t2v[3].y));
        *(uint4*)&hsb[n*12+4] = make_uint4(
            pk2(t2v[4].x,t2v[4].y), pk2(t2v[5].x,t2v[5].y),
            pk2(t2v[6].x,t2v[6].y), pk2(t2v[7].x,t2v[7].y));
        *(uint4*)&hsb[n*12+8] = make_uint4(
            pk2(t2v[8].x,t2v[8].y), pk2(t2v[9].x,t2v[9].y),
            pk2(t2v[10].x,t2v[10].y), pk2(t2v[11].x,t2v[11].y));
        __syncthreads();   // t2 rows visible

        // ---- phase 2: B1 frags (own rows), 32 MFMAs, pack, D -> own rows ----
        uint4 b1[4];
        #pragma unroll
        for(int i=0;i<4;++i) b1[i]=make_uint4(0,0,0,0);
        if(lane < 48){
            #pragma unroll
            for(int i=0;i<4;++i){
                int nn_ = wv*64 + i*16 + (lane&15);
                b1[i] = *(const uint4*)&hsb[nn_*12 + ((lane>>4)<<2)];
            }
        }
        uint2 pa[4], pb[4];
        #pragma unroll
        for(int i=0;i<4;++i){
            f32x4 Da = {biA[0],biA[1],biA[2],biA[3]};
            f32x4 Db = {biB[0],biB[1],biB[2],biB[3]};
            Da = MF(wsHiA, b0[i], Da);
            Da = MF(wsLoA, b0[i], Da);
            Da = MF(wnHiA, b1[i], Da);
            Da = MF(wnLoA, b1[i], Da);
            Db = MF(wsHiB, b0[i], Db);
            Db = MF(wsLoB, b0[i], Db);
            Db = MF(wnHiB, b1[i], Db);
            Db = MF(wnLoB, b1[i], Db);
            pa[i] = make_uint2(pk2(Da[0],Da[1]), pk2(Da[2],Da[3]));
            pb[i] = make_uint2(pk2(Db[0],Db[1]), pk2(Db[2],Db[3]));
        }
        __syncthreads();   // all B1 reads done before D overwrites rows
        #pragma unroll
        for(int i=0;i<4;++i){
            int nn_ = wv*64 + i*16 + (lane&15);
            int o = (lane>>4)*2;           // uints {0,2,4,6}: m = 2o..2o+3
            *(uint2*)&hsb[nn_*12 + o] = pa[i];
            if(lane < 32){                 // m = 16..23 -> uints {8,10}
                *(uint2*)&hsb[nn_*12 + 8 + (lane>>4)*2] = pb[i];
            }
        }
        __syncthreads();   // D visible for next layer's gather / writeback
    }
    for(int i=tid;i<1536;i+=512) ((uint4*)base)[i] = ((const uint4*)hsb)[i];
}

// ---- merged f1+f2: blocks [0,512) = f1 role, [512,1024) = f2 ----
#define F2S 25
__global__ __launch_bounds__(256) void k_f12(const unsigned* h, fp w1, fp w2,
        float* f1, float* f2){
    __shared__ float red[256*F2S];
    int tid = threadIdx.x;
    if(blockIdx.x < 512){
        // f1[b,l,n] = sum_c sg(gate)*lk(filt)*w1[c]
        if(tid < 192){
            int blk = blockIdx.x; int b = blk>>6; int n0 = (blk&63)*8;
            float acc = 0.f;
            const unsigned* fb = h + (size_t)b*CO*NT + n0*12;
            const unsigned* gb = fb + (size_t)CO*(NT/2);
            int e = tid;
            for(int c=0;c<CO;++c){
                float w = w1[c];
                unsigned f = fb[(size_t)c*(NT/2) + (e>>1)];
                unsigned g = gb[(size_t)c*(NT/2) + (e>>1)];
                float fv = (e&1) ? hi2f(f) : lo2f(f);
                float gv = (e&1) ? hi2f(g) : lo2f(g);
                acc += sg(gv)*lk(fv)*w;
            }
            int nl = e/TT, t = e%TT;
            f1[(b*TT+t)*NN + n0+nl] = acc;
        }
        return;
    }
    // f2[b,c,l] = sum_n sg(gate)*lk(filt)*w2[n]
    int blk = blockIdx.x - 512; int b = blk/CO; int c = blk%CO;
    float acc[TT];
    #pragma unroll
    for(int l=0;l<TT;++l) acc[l]=0.f;
    const unsigned* fb = h + (size_t)b*CO*NT + (size_t)c*(NT/2);
    const unsigned* gb = fb + (size_t)CO*(NT/2);
    for(int n=tid;n<NN;n+=256){
        float w = w2[n];
        #pragma unroll
        for(int k=0;k<3;++k){
            uint4 f = *(const uint4*)(fb + n*12 + 4*k);
            uint4 g = *(const uint4*)(gb + n*12 + 4*k);
            acc[8*k  ] += sg(lo2f(g.x))*lk(lo2f(f.x))*w;
            acc[8*k+1] += sg(hi2f(g.x))*lk(hi2f(f.x))*w;
            acc[8*k+2] += sg(lo2f(g.y))*lk(lo2f(f.y))*w;
            acc[8*k+3] += sg(hi2f(g.y))*lk(hi2f(f.y))*w;
            acc[8*k+4] += sg(lo2f(g.z))*lk(lo2f(f.z))*w;
            acc[8*k+5] += sg(hi2f(g.z))*lk(hi2f(f.z))*w;
            acc[8*k+6] += sg(lo2f(g.w))*lk(lo2f(f.w))*w;
            acc[8*k+7] += sg(hi2f(g.w))*lk(hi2f(f.w))*w;
        }
    }
    #pragma unroll
    for(int l=0;l<TT;++l) red[tid*F2S+l]=acc[l];
    __syncthreads();
    for(int s=128;s>0;s>>=1){
        if(tid<s){
            #pragma unroll
            for(int l=0;l<TT;++l) red[tid*F2S+l]+=red[(tid+s)*F2S+l];
        }
        __syncthreads();
    }
    if(tid<TT) f2[(b*CO+c)*TT+tid] = red[tid];
}

// ---- merged dilated convs: blocks 0..31 = conv over n on f1; 32..39 = over l on f2 ----
__global__ __launch_bounds__(256) void k_convf(fp f1, fp wd1, float* f1c,
        fp f2, fp wd2, float* f2c){
    __shared__ float sm[9856];            // union: f1 path 4272 fl, f2 path 9856 fl
    int tid=threadIdx.x;
    if(blockIdx.x < 32){
        float* fs  = sm;                  // [TT][130]
        float* w0  = sm + 3120;
        float* w1a = sm + 3696;
        int bid = blockIdx.x; int b = bid>>2; int n0 = (bid&3)*128;
        for(int i=tid;i<TT*130;i+=256){
            int l=i/130, col=i%130; int n = n0+col-1;
            fs[l*130+col] = (n>=0 && n<NN) ? f1[(b*TT+l)*NN+n] : 0.f;
        }
        for(int i=tid;i<TT*TT;i+=256){ w0[i]=wd1[i*2]; w1a[i]=wd1[i*2+1]; }
        __syncthreads();
        for(int j=tid;j<TT*128;j+=256){
            int o=j>>7, nn=j&127;
            float acc=0.f;
            #pragma unroll
            for(int i=0;i<TT;++i) acc += fs[i*130+nn]*w0[o*TT+i] + fs[i*130+nn+2]*w1a[o*TT+i];
            f1c[(b*TT+o)*NN+n0+nn]=acc;
        }
        return;
    }
    float* fs  = sm;                      // [CO][TT+2]
    float* w0  = sm + 1664;
    float* w1a = sm + 5760;
    int b = blockIdx.x - 32;
    for(int i=tid;i<CO*TT;i+=256){ int c=i/TT,l=i%TT; fs[c*26+l+1]=f2[(b*CO+c)*TT+l]; }
    for(int c=tid;c<CO;c+=256){ fs[c*26]=0.f; fs[c*26+TT+1]=0.f; }
    for(int i=tid;i<CO*CO;i+=256){ w0[i]=wd2[i*2]; w1a[i]=wd2[i*2+1]; }
    __syncthreads();
    for(int j=tid;j<CO*TT;j+=256){
        int o=j/TT, l=j%TT;
        float acc=0.f;
        for(int i=0;i<CO;++i) acc += fs[i*26+l]*w0[o*CO+i] + fs[i*26+l+2]*w1a[o*CO+i];
        f2c[(b*CO+o)*TT+l]=acc;
    }
}

// ---------------- g1[b,l,c] = sum_n f1c[b,l,n]*tW[n,c] ----------------
__global__ __launch_bounds__(384) void k_g1(fp f1c, fp tW, float* g1){
    __shared__ float fs[6*NN];
    int blk=blockIdx.x; int b=blk>>2; int part=blk&3;
    int tid=threadIdx.x;
    for(int i=tid;i<6*NN;i+=384) fs[i]=f1c[b*TT*NN + part*6*NN + i];
    __syncthreads();
    int c = tid & 63; int r = tid >> 6;   // r = 0..5
    float acc=0.f;
    for(int n=0;n<NN;++n) acc += fs[r*NN + n]*tW[n*CO + c];
    g1[(b*TT + part*6 + r)*CO + c] = acc;
}

// -------- logits: A = sig matmul (18 blk); BC = t_v matmul + BN + softmax (1 blk) --
__global__ __launch_bounds__(256) void k_lgA(fp g1, fp f2c, fp tbias, float* sig){
    int j = blockIdx.x*256 + threadIdx.x;
    int b=j/(TT*TT); int r=j%(TT*TT); int l=r/TT; int q=r%TT;
    float acc = tbias[l*TT+q];
    fp gg = g1 + (b*TT+l)*CO;
    fp ff = f2c + b*CO*TT + q;
    for(int c=0;c<CO;++c) acc += gg[c]*ff[c*TT];
    sig[j] = sg(acc);
}
__global__ __launch_bounds__(256) void k_lgBC(fp tv, const float* sig,
        fp bng, fp bnb, float* coefs, float* tco){
    __shared__ float lg2[B_*TT*TT];       // 18.4 KB
    __shared__ float muq[TT], scq[TT], shq[TT];
    int tid=threadIdx.x;
    for(int j=tid;j<B_*TT*TT;j+=256){
        int b=j/(TT*TT); int r=j%(TT*TT); int l=r/TT; int q=r%TT;
        float acc=0.f;
        for(int k=0;k<TT;++k) acc += tv[l*TT+k]*sig[(b*TT+k)*TT+q];
        lg2[j]=acc;
    }
    __syncthreads();
    if(tid<TT){
        int q=tid;
        float s=0.f;
        for(int b=0;b<B_;++b) for(int l=0;l<TT;++l) s += lg2[(b*TT+l)*TT+q];
        float mu = s/192.f;
        float v=0.f;
        for(int b=0;b<B_;++b) for(int l=0;l<TT;++l){ float d = lg2[(b*TT+l)*TT+q]-mu; v += d*d; }
        v = fmaxf(v/192.f, 0.f);
        muq[q]=mu; scq[q]=rsqrtf(v+EPSL)*bng[q]; shq[q]=bnb[q];
    }
    __syncthreads();
    if(tid<192){
        int b=tid/TT, l=tid%TT;
        int base = (l<12)?0:12;
        float z[12];
        float mx=-1e30f;
        #pragma unroll
        for(int r=0;r<12;++r){
            int q=base+r;
            float zv=(lg2[(b*TT+l)*TT+q]-muq[q])*scq[q]+shq[q];
            z[r]=zv; mx = fmaxf(mx,zv);
        }
        float s=0.f;
        #pragma unroll
        for(int r=0;r<12;++r){ z[r]=expf(z[r]-mx); s+=z[r]; }
        float is=1.f/s;
        for(int q=0;q<TT;++q){
            float cf = (q>=base && q<base+12) ? z[q-base]*is : 0.f;
            coefs[(b*TT+l)*TT+q]=cf;
            tco[(b*TT+q)*TT+l]=cf;
        }
    }
}

// ---- x1new = xg @ coefs^T ; y = leaky(x1new)+x_input ; LN stats ----
__global__ __launch_bounds__(256, 4) void k_apply(const unsigned* h, fp xin, fp coefs,
        float* y, float* stats){
    __shared__ __attribute__((aligned(16))) float cf[TT*TT];
    __shared__ float red[256];
    int blk=blockIdx.x; int b=blk>>7; int c=(blk>>1)&63; int half=blk&1;
    int tid=threadIdx.x;
    for(int i=tid;i<TT*TT;i+=256) cf[i]=coefs[b*TT*TT+i];
    __syncthreads();
    int n = half*256 + tid;
    const unsigned* fb = h + (size_t)b*CO*NT + (size_t)c*(NT/2) + n*12;
    const unsigned* gb = fb + (size_t)CO*(NT/2);
    fp xrow = xin + (size_t)(b*CO+c)*NT + n*TT;
    float* yrow = y + (size_t)(b*CO+c)*NT + n*TT;
    float row[TT];
    #pragma unroll
    for(int k=0;k<3;++k){
        uint4 f = *(const uint4*)(fb + 4*k);
        uint4 g = *(const uint4*)(gb + 4*k);
        row[8*k  ] = sg(lo2f(g.x))*lk(lo2f(f.x));
        row[8*k+1] = sg(hi2f(g.x))*lk(hi2f(f.x));
        row[8*k+2] = sg(lo2f(g.y))*lk(lo2f(f.y));
        row[8*k+3] = sg(hi2f(g.y))*lk(hi2f(f.y));
        row[8*k+4] = sg(lo2f(g.z))*lk(lo2f(f.z));
        row[8*k+5] = sg(hi2f(g.z))*lk(hi2f(f.z));
        row[8*k+6] = sg(lo2f(g.w))*lk(lo2f(f.w));
        row[8*k+7] = sg(hi2f(g.w))*lk(hi2f(f.w));
    }
    float ls=0.f, lsq=0.f;
    #pragma unroll
    for(int k=0;k<6;++k){
        float4 u = *(const float4*)(xrow + 4*k);
        float a[4];
        #pragma unroll
        for(int j=0;j<4;++j){
            const float4* crow = (const float4*)&cf[(4*k+j)*TT];
            float acc=0.f;
            #pragma unroll
            for(int kk=0;kk<6;++kk){
                float4 cv = crow[kk];
                acc += row[4*kk  ]*cv.x;
                acc += row[4*kk+1]*cv.y;
                acc += row[4*kk+2]*cv.z;
                acc += row[4*kk+3]*cv.w;
            }
            a[j]=acc;
        }
        float y0 = lk(a[0])+u.x, y1 = lk(a[1])+u.y, y2 = lk(a[2])+u.z, y3 = lk(a[3])+u.w;
        *(float4*)(yrow + 4*k) = make_float4(y0,y1,y2,y3);
        ls  += y0+y1+y2+y3;
        lsq += y0*y0+y1*y1+y2*y2+y3*y3;
    }
    red[tid]=ls; __syncthreads();
    for(int s=128;s>0;s>>=1){ if(tid<s) red[tid]+=red[tid+s]; __syncthreads(); }
    float t0=red[0]; __syncthreads();
    red[tid]=lsq; __syncthreads();
    for(int s=128;s>0;s>>=1){ if(tid<s) red[tid]+=red[tid+s]; __syncthreads(); }
    if(tid==0){ atomicAdd(&stats[32+b], t0); atomicAdd(&stats[40+b], red[0]); }
}

// ---------------- final LN apply; stats finalize inlined ----------------
__global__ void k_final(fp y, fp lng, fp lnb, const float* stats, float* out){
    float mb[8], sb[8];
    #pragma unroll
    for(int b=0;b<8;++b){
        float mm = stats[32+b] / (float)LNCNT;
        float vv = fmaxf(stats[40+b] / (float)LNCNT - mm*mm, 0.f);
        mb[b]=mm; sb[b]=rsqrtf(vv + EPSL);
    }
    int tot = B_*CO*NT;
    for(int i = blockIdx.x*blockDim.x + threadIdx.x; i<tot; i+=gridDim.x*blockDim.x){
        int b = i/LNCNT; int r = i%LNCNT;
        out[i] = (y[i]-mb[b])*sb[b]*lng[r]+lnb[r];
    }
}

extern "C" void kernel_launch(void* const* d_in, const int* in_sizes, int n_in,
                              void* d_out, int out_size, void* d_ws, size_t ws_size,
                              hipStream_t stream){
    fp x    = (fp)d_in[0];
    fp adj  = (fp)d_in[1];
    fp w1   = (fp)d_in[2];
    fp b1   = (fp)d_in[3];
    fp wt   = (fp)d_in[4];
    fp bt   = (fp)d_in[5];
    fp lng  = (fp)d_in[6];
    fp lnb  = (fp)d_in[7];
    fp s0ws = (fp)d_in[8];
    fp s0wn = (fp)d_in[9];
    fp s0b  = (fp)d_in[10];
    fp s1ws = (fp)d_in[11];
    fp s1wn = (fp)d_in[12];
    fp s1b  = (fp)d_in[13];
    fp tw1  = (fp)d_in[14];
    fp tw2  = (fp)d_in[15];
    fp twd1 = (fp)d_in[16];
    fp twd2 = (fp)d_in[17];
    fp tW   = (fp)d_in[18];
    fp tbias= (fp)d_in[19];
    fp tv   = (fp)d_in[20];
    fp bng  = (fp)d_in[21];
    fp bnb  = (fp)d_in[22];

    float* W = (float*)d_ws;            // stats [0..63]
    int*   CNTp = (int*)(W+256);        // 512 ints
    int*   PERM = (int*)(W+768);        // 512 ints (old DEG slot)
    int*   IDXp = (int*)(W+1280);
    float* VALp = W+34048;
    float* F1   = W+66816;
    float* F1C  = W+165120;
    float* F2   = W+263424;
    float* F2C  = W+275712;
    float* G1   = W+288000;
    float* CF   = W+300288;
    float* XIN  = W+304896;
    float* X1   = W+6596352;
    float* SIG  = W+6596352;            // reuse X1 head (dead after hbuild)
    uint4* WFq  = (uint4*)(W+12887808); // sage weight frags: 1024 uint4 = 16KB
    uint4* WCF  = (uint4*)(W+12891904); // conv weight frags: 2048 uint4 = 32KB
    unsigned* HA = (unsigned*)(W+19179264);   // packed bf16 h: 6291456 uints
    float* Y    = W+31762176;           // ends 38053632 floats = 152.2 MB
    float* LG2  = SIG + 4608;

    float* oout   = (float*)d_out;
    float* o_adj  = oout + 6291456;
    float* o_tc   = oout + 6291456 + 262144;

    hipMemsetAsync(W, 0, 768*sizeof(float), stream);   // stats + cnt
    k_cscw<<<1025,256,0,stream>>>(adj, CNTp, IDXp, VALp, o_adj,
                                  s0ws, s0wn, s1ws, s1wn, WFq, w1, wt, WCF);
    k_perm<<<1,512,0,stream>>>(CNTp, PERM);
    k_conv<<<512,256,0,stream>>>(x, WCF, b1, bt, XIN, X1, W);
    k_hbuild<<<512,512,0,stream>>>(X1, lng, lnb, W, CNTp, IDXp, VALp, PERM, HA);
    k_sageF<<<1024,512,0,stream>>>(HA, WFq, s0b, s1b, CNTp, IDXp, PERM);
    k_f12<<<1024,256,0,stream>>>(HA, tw1, tw2, F1, F2);
    k_convf<<<40,256,0,stream>>>(F1, twd1, F1C, F2, twd2, F2C);
    k_g1<<<32,384,0,stream>>>(F1C, tW, G1);
    k_lgA<<<18,256,0,stream>>>(G1, F2C, tbias, SIG);
    k_lgBC<<<1,256,0,stream>>>(tv, SIG, bng, bnb, CF, o_tc);
    k_apply<<<1024,256,0,stream>>>(HA, XIN, CF, Y, W);
    k_final<<<2048,256,0,stream>>>(Y, lng, lnb, W, oout);
}

// Round 15
// 327.470 us; speedup vs baseline: 1.1743x; 1.0570x over previous
//
#include <hip/hip_runtime.h>
#include <hip/hip_bf16.h>
#include <math.h>

#define B_    8
#define CIN   32
#define CO    64
#define NN    512
#define TT    24
#define NT    (NN*TT)        /* 12288 */
#define LNCNT (CO*NT)        /* 786432 */
#define EPSL  1e-5f
#define MAXNZ 64
#define HSS   28             /* fp32 LDS row stride (hbuild) */

typedef const float* fp;
static __device__ __forceinline__ float lk(float x){ return x > 0.f ? x : 0.01f*x; }
static __device__ __forceinline__ float sg(float x){
    if(x >= 0.f){ float e = expf(-x); return 1.f/(1.f+e); }
    float e = expf(x); return e/(1.f+e);
}
// bf16 pair pack/unpack (lo = even element, hi = odd element)
static __device__ __forceinline__ unsigned pk2(float a, float b){
    __hip_bfloat16 x = __float2bfloat16(a), y = __float2bfloat16(b);
    unsigned lo = *(unsigned short*)&x, hi = *(unsigned short*)&y;
    return lo | (hi<<16);
}
static __device__ __forceinline__ float lo2f(unsigned u){ return __uint_as_float(u<<16); }
static __device__ __forceinline__ float hi2f(unsigned u){ return __uint_as_float(u & 0xffff0000u); }

// load 8 weights w[m][kb..kb+7] (T=24 bounds -> 0 pad), split hi/lo bf16 frags
static __device__ __forceinline__ void ldw_split(fp w, int m, int kb, uint4* hi, uint4* lo){
    float vh[8], vl[8];
    #pragma unroll
    for(int j=0;j<8;++j){
        float v = (m < TT && (kb+j) < TT) ? w[m*TT + kb + j] : 0.f;
        __hip_bfloat16 hb = __float2bfloat16(v);
        float hf = __bfloat162float(hb);
        vh[j] = hf;
        vl[j] = v - hf;
    }
    *hi = make_uint4(pk2(vh[0],vh[1]),pk2(vh[2],vh[3]),pk2(vh[4],vh[5]),pk2(vh[6],vh[7]));
    *lo = make_uint4(pk2(vl[0],vl[1]),pk2(vl[2],vl[3]),pk2(vl[4],vl[5]),pk2(vl[6],vl[7]));
}

// ---- merged CSC build (blocks 0..1023) + weight frag prep (block 1024) ----
// NOTE (round 12 lesson): NO cooperative launches in this harness.
__global__ __launch_bounds__(256) void k_cscw(fp adj, int* cnt, int* idx, float* val,
        float* o_adj, fp s0ws, fp s0wn, fp s1ws, fp s1wn, uint4* wf,
        fp w1, fp wt, uint4* wcf){
    if(blockIdx.x < 1024){
        int e = blockIdx.x*256 + threadIdx.x;   // 0 .. NN*NN-1 exactly
        float a = adj[e];
        o_adj[e] = a;                           // replaces the D2D memcpy launch
        if(a != 0.f){
            int u = e >> 9, q = e & 511;
            int slot = atomicAdd(&cnt[q], 1);
            if(slot < MAXNZ){ idx[q*MAXNZ+slot] = u; val[q*MAXNZ+slot] = a; }
        }
        return;
    }
    int t = threadIdx.x;
    int lane = t & 63, g = t >> 6;
    {   // sage weights
        int M = g >> 1, H = g & 1;
        int m  = H*16 + (lane&15);
        int kb = (lane>>4)*8;
        for(int L=0; L<2; ++L){
            fp w = L ? (M ? s1wn : s1ws) : (M ? s0wn : s0ws);
            uint4 hi, lo;
            ldw_split(w, m, kb, &hi, &lo);
            wf[L*512 + g*128 +      lane] = hi;
            wf[L*512 + g*128 + 64 + lane] = lo;
        }
    }
    {   // conv weights
        int kb = (lane>>4)*8;
        for(int ot=0; ot<4; ++ot){
            int m = ot*16 + (lane&15);
            float vh[8], vl[8];
            #pragma unroll
            for(int j=0;j<8;++j){
                int c = kb+j;
                float v = (g==0) ? w1[m*CIN+c] : wt[(m*CIN+c)*3 + (g-1)];
                __hip_bfloat16 hb = __float2bfloat16(v);
                float hf = __bfloat162float(hb);
                vh[j]=hf; vl[j]=v-hf;
            }
            wcf[ot*512 + g*128 +      lane] = make_uint4(
                pk2(vh[0],vh[1]),pk2(vh[2],vh[3]),pk2(vh[4],vh[5]),pk2(vh[6],vh[7]));
            wcf[ot*512 + g*128 + 64 + lane] = make_uint4(
                pk2(vl[0],vl[1]),pk2(vl[2],vl[3]),pk2(vl[4],vl[5]),pk2(vl[6],vl[7]));
        }
    }
}

// ---- degree-sorted node permutation: counting sort, 1 block ----
__global__ __launch_bounds__(512) void k_perm(const int* cnt, int* perm){
    __shared__ int hist[65];
    __shared__ int base[65];
    int tid = threadIdx.x;
    if(tid < 65) hist[tid] = 0;
    __syncthreads();
    int c0 = cnt[tid];
    int c = c0 < 0 ? 0 : (c0 > 64 ? 64 : c0);
    atomicAdd(&hist[c], 1);
    __syncthreads();
    if(tid == 0){
        int s = 0;
        for(int i=0;i<65;++i){ base[i] = s; s += hist[i]; }
    }
    __syncthreads();
    int pos = atomicAdd(&base[c], 1);
    perm[pos] = tid;
}

typedef __attribute__((ext_vector_type(8))) short bf16x8;
typedef __attribute__((ext_vector_type(4))) float f32x4;
typedef __attribute__((ext_vector_type(2))) float f32x2;

static __device__ __forceinline__ f32x4 MF(uint4 a, uint4 b, f32x4 c){
    union { uint4 u; bf16x8 v; } A, Bv; A.u = a; Bv.u = b;
    return __builtin_amdgcn_mfma_f32_16x16x32_bf16(A.v, Bv.v, c, 0, 0, 0);
}

// ======================= MFMA conv1 + temporal conv + LN stats ================
#define XST 20
__global__ __launch_bounds__(256, 4) void k_conv(fp x, const uint4* wcf, fp b1, fp bt,
        float* xin, float* x1p, float* stats){
    __shared__ __attribute__((aligned(16))) unsigned xh[208*XST];
    __shared__ __attribute__((aligned(16))) unsigned xl[208*XST];
    __shared__ float red[256];
    int bid = blockIdx.x; int b = bid>>6; int n0 = (bid&63)*8;
    int tid = threadIdx.x; int lane = tid&63; int w = tid>>6;
    for(int i=tid;i<3072;i+=256){
        int cp = i/192; int r = i-cp*192; int node = r/24; int t = r-node*24;
        const float* xp = x + ((size_t)(b*CIN + 2*cp)*NN + n0+node)*TT + t;
        float a = xp[0], b2 = xp[NT];
        __hip_bfloat16 ab = __float2bfloat16(a), bb = __float2bfloat16(b2);
        float ah = __bfloat162float(ab), bh = __bfloat162float(bb);
        int row = node*26 + t + 1;
        xh[row*XST+cp] = pk2(ah, bh);
        xl[row*XST+cp] = pk2(a-ah, b2-bh);
    }
    {   // zero guard rows (t=-1 and t=24 per node): 8*2*16 = 256 slots
        int node = tid>>5; int which = (tid>>4)&1; int j = tid&15;
        int row = node*26 + which*25;
        xh[row*XST+j]=0; xl[row*XST+j]=0;
    }
    const uint4* wb = wcf + w*512;
    uint4 h1 = wb[      lane], l1 = wb[ 64+lane];
    uint4 ht0= wb[128 + lane], lt0= wb[192+lane];
    uint4 ht1= wb[256 + lane], lt1= wb[320+lane];
    uint4 ht2= wb[384 + lane], lt2= wb[448+lane];
    int mrow = (lane>>4)*4;
    float bi0[4], bi1[4];
    #pragma unroll
    for(int r2=0;r2<4;++r2){
        int o = w*16 + mrow + r2;
        bi0[r2]=b1[o]; bi1[r2]=bt[o];
    }
    __syncthreads();
    float ls=0.f, lsq=0.f;
    int kb4 = (lane>>4)*4;
    for(int pt=0; pt<12; ++pt){
        int p = pt*16 + (lane&15);
        int node = p/24, t = p-node*24;
        int rc = (node*26 + t + 1)*XST;
        uint4 Bhm = *(const uint4*)&xh[rc - XST + kb4];
        uint4 Blm = *(const uint4*)&xl[rc - XST + kb4];
        uint4 Bhc = *(const uint4*)&xh[rc       + kb4];
        uint4 Blc = *(const uint4*)&xl[rc       + kb4];
        uint4 Bhp = *(const uint4*)&xh[rc + XST + kb4];
        uint4 Blp = *(const uint4*)&xl[rc + XST + kb4];
        f32x4 D0 = {bi0[0],bi0[1],bi0[2],bi0[3]};
        f32x4 D1 = {bi1[0],bi1[1],bi1[2],bi1[3]};
        D0 = MF(h1, Bhc, D0); D0 = MF(l1, Bhc, D0); D0 = MF(h1, Blc, D0);
        D1 = MF(ht0,Bhm, D1); D1 = MF(lt0,Bhm, D1); D1 = MF(ht0,Blm, D1);
        D1 = MF(ht1,Bhc, D1); D1 = MF(lt1,Bhc, D1); D1 = MF(ht1,Blc, D1);
        D1 = MF(ht2,Bhp, D1); D1 = MF(lt2,Bhp, D1); D1 = MF(ht2,Blp, D1);
        size_t gbase = ((size_t)(b*CO + w*16 + mrow)*NN + n0+node)*TT + t;
        #pragma unroll
        for(int r2=0;r2<4;++r2){
            xin[gbase + (size_t)r2*NT] = D0[r2];
            x1p[gbase + (size_t)r2*NT] = D1[r2];
            ls  += D1[r2];
            lsq += D1[r2]*D1[r2];
        }
    }
    red[tid]=ls; __syncthreads();
    for(int s=128;s>0;s>>=1){ if(tid<s) red[tid]+=red[tid+s]; __syncthreads(); }
    float tsum = red[0]; __syncthreads();
    red[tid]=lsq; __syncthreads();
    for(int s=128;s>0;s>>=1){ if(tid<s) red[tid]+=red[tid+s]; __syncthreads(); }
    if(tid==0){ atomicAdd(&stats[b], tsum); atomicAdd(&stats[8+b], red[0]); }
}

// ---- LN+leaky (fused) then h = stack(4*x1, adj^T x1); h stored packed bf16 ----
__global__ __launch_bounds__(512, 4) void k_hbuild(fp x1p, fp lng, fp lnb,
        const float* stats, const int* cnt, const int* idx, const float* val,
        const int* perm, unsigned* h){
    __shared__ float xs[NN*HSS];          // 57.3 KB
    int blk = blockIdx.x; int b = blk >> 6; int c = blk & 63;
    int tid = threadIdx.x;
    float mm = stats[b] / (float)LNCNT;
    float vv = fmaxf(stats[8+b] / (float)LNCNT - mm*mm, 0.f);
    float m = mm, inv = rsqrtf(vv + EPSL);
    fp src  = x1p + (size_t)(b*CO + c)*NT;
    fp gsrc = lng + (size_t)c*NT;
    fp bsrc = lnb + (size_t)c*NT;
    for(int i4=tid;i4<NT/4;i4+=512){
        int i = i4*4;
        int n = i/TT, t = i-n*TT;
        float4 s  = *(const float4*)(src + i);
        float4 g  = *(const float4*)(gsrc + i);
        float4 bb = *(const float4*)(bsrc + i);
        *(float4*)&xs[n*HSS + t] = make_float4(
            lk((s.x-m)*inv*g.x+bb.x), lk((s.y-m)*inv*g.y+bb.y),
            lk((s.z-m)*inv*g.z+bb.z), lk((s.w-m)*inv*g.w+bb.w));
    }
    int n = perm[tid];
    int c0 = cnt[n];
    int cq = c0 > MAXNZ ? MAXNZ : c0;
    int4 j0 = *(const int4*)&idx[n*MAXNZ+0];   // prefetch (entries >= cq unused)
    int4 j1 = *(const int4*)&idx[n*MAXNZ+4];
    int4 j2 = *(const int4*)&idx[n*MAXNZ+8];
    float4 v0 = *(const float4*)&val[n*MAXNZ+0];
    float4 v1 = *(const float4*)&val[n*MAXNZ+4];
    float4 v2 = *(const float4*)&val[n*MAXNZ+8];
    __syncthreads();
    float acc[TT];
    #pragma unroll
    for(int l=0;l<TT;++l) acc[l]=0.f;
#define HB(J,U,V) if((J)<cq){ const float4* rp=(const float4*)&xs[(U)*HSS]; \
    _Pragma("unroll") for(int k=0;k<6;++k){ float4 wv=rp[k]; \
        acc[4*k]+=(V)*wv.x; acc[4*k+1]+=(V)*wv.y; acc[4*k+2]+=(V)*wv.z; acc[4*k+3]+=(V)*wv.w; } }
    HB(0,j0.x,v0.x) HB(1,j0.y,v0.y) HB(2,j0.z,v0.z) HB(3,j0.w,v0.w)
    HB(4,j1.x,v1.x) HB(5,j1.y,v1.y) HB(6,j1.z,v1.z) HB(7,j1.w,v1.w)
    HB(8,j2.x,v2.x) HB(9,j2.y,v2.y) HB(10,j2.z,v2.z) HB(11,j2.w,v2.w)
    for(int j=12;j<cq;++j){
        int u = idx[n*MAXNZ+j]; float v = val[n*MAXNZ+j];
        const float4* rp = (const float4*)&xs[u*HSS];
        #pragma unroll
        for(int k=0;k<6;++k){ float4 wv=rp[k];
            acc[4*k]+=v*wv.x; acc[4*k+1]+=v*wv.y; acc[4*k+2]+=v*wv.z; acc[4*k+3]+=v*wv.w; }
    }
    float t1[TT];
    const float4* sp = (const float4*)&xs[n*HSS];
    #pragma unroll
    for(int k=0;k<6;++k){
        float4 v = sp[k];
        t1[4*k]=v.x; t1[4*k+1]=v.y; t1[4*k+2]=v.z; t1[4*k+3]=v.w;
    }
    unsigned* h0 = h + (size_t)((b*CO+c)*2)*(NT/2);
    unsigned* h1 = h0 + NT/2;
    #pragma unroll
    for(int k=0;k<3;++k){
        *(uint4*)(h0 + n*12 + 4*k) = make_uint4(
            pk2(4.f*t1[8*k],  4.f*t1[8*k+1]), pk2(4.f*t1[8*k+2],4.f*t1[8*k+3]),
            pk2(4.f*t1[8*k+4],4.f*t1[8*k+5]), pk2(4.f*t1[8*k+6],4.f*t1[8*k+7]));
        *(uint4*)(h1 + n*12 + 4*k) = make_uint4(
            pk2(acc[8*k],  acc[8*k+1]), pk2(acc[8*k+2],acc[8*k+3]),
            pk2(acc[8*k+4],acc[8*k+5]), pk2(acc[8*k+6],acc[8*k+7]));
    }
}

// ======================= MFMA-based fused GraphSAGE x2 =======================
static __device__ __forceinline__ void acc8v(f32x2* t, uint4 q){
    t[0] += (f32x2){lo2f(q.x), hi2f(q.x)};
    t[1] += (f32x2){lo2f(q.y), hi2f(q.y)};
    t[2] += (f32x2){lo2f(q.z), hi2f(q.z)};
    t[3] += (f32x2){lo2f(q.w), hi2f(q.w)};
}

#define GBODY(u) { int ro=(u)*12; \
    uint4 q0=*(const uint4*)&hsb[ro]; \
    uint4 q1=*(const uint4*)&hsb[ro+4]; \
    uint4 q2=*(const uint4*)&hsb[ro+8]; \
    acc8v(t2v,q0); acc8v(t2v+4,q1); acc8v(t2v+8,q2); }
#define GSTEP(J,U) if((J)<cq) GBODY(U)

__global__ __launch_bounds__(512, 4) void k_sageF(unsigned* h, const uint4* wf,
        fp s0b, fp s1b, const int* cnt, const int* idx, const int* perm){
    __shared__ unsigned hsb[NN*12];       // 24 KB, the ONLY buffer
    int tid  = threadIdx.x;
    int lane = tid & 63;
    int wv   = tid >> 6;
    unsigned* base = h + (size_t)blockIdx.x*(NT/2);

    for(int i=tid;i<1536;i+=512) ((uint4*)hsb)[i] = ((const uint4*)base)[i];
    int n  = perm[tid];        // gather: this thread owns node n (deg-balanced)
    int c0 = cnt[n];
    float di = 1.f / (float)(c0 < 1 ? 1 : c0);
    int cq = c0 > MAXNZ ? MAXNZ : c0;
    int4 i0 = *(const int4*)&idx[n*MAXNZ+0];   // prefetch (entries >= cq unused)
    int4 i1 = *(const int4*)&idx[n*MAXNZ+4];
    int4 i2 = *(const int4*)&idx[n*MAXNZ+8];
    __syncthreads();

    for(int layer=0; layer<2; ++layer){
        const uint4* wl = wf + layer*512;
        uint4 wsHiA = wl[      lane], wsLoA = wl[ 64+lane];
        uint4 wsHiB = wl[128 + lane], wsLoB = wl[192+lane];
        uint4 wnHiA = wl[256 + lane], wnLoA = wl[320+lane];
        uint4 wnHiB = wl[384 + lane], wnLoB = wl[448+lane];
        fp Bp = layer ? s1b : s0b;
        float biA[4], biB[4];
        #pragma unroll
        for(int r=0;r<4;++r){
            biA[r] = Bp[(lane>>4)*4 + r];
            int m2 = 16 + (lane>>4)*4 + r;
            biB[r] = (m2 < TT) ? Bp[m2] : 0.f;
        }

        // ---- phase 1: gather t2 (reads hsb); load B0 frags (own rows) ----
        f32x2 t2v[12];
        #pragma unroll
        for(int l=0;l<12;++l) t2v[l] = (f32x2){0.f,0.f};
        GSTEP(0,i0.x) GSTEP(1,i0.y) GSTEP(2,i0.z) GSTEP(3,i0.w)
        GSTEP(4,i1.x) GSTEP(5,i1.y) GSTEP(6,i1.z) GSTEP(7,i1.w)
        GSTEP(8,i2.x) GSTEP(9,i2.y) GSTEP(10,i2.z) GSTEP(11,i2.w)
        for(int j=12;j<cq;++j){ int u=idx[n*MAXNZ+j]; GBODY(u) }
        #pragma unroll
        for(int l=0;l<12;++l) t2v[l] *= di;

        uint4 b0[4];
        #pragma unroll
        for(int i=0;i<4;++i) b0[i]=make_uint4(0,0,0,0);
        if(lane < 48){
            #pragma unroll
            for(int i=0;i<4;++i){
                int nn_ = wv*64 + i*16 + (lane&15);
                b0[i] = *(const uint4*)&hsb[nn_*12 + ((lane>>4)<<2)];
            }
        }
        __syncthreads();   // ALL hsb reads (gather + B0, all waves) complete

        // ---- t2 pack -> own hsb row (input slab now dead) ----
        *(uint4*)&hsb[n*12  ] = make_uint4(
            pk2(t2v[0].x,t2v[0].y), pk2(t2v[1].x,t2v[1].y),
            pk2(t2v[2].x,t2v[2].y), pk2(t2v[3].x,t2v[3].y));
        *(uint4*)&hsb[n*12+4] = make_uint4(
            pk2(t2v[4].x,t2v[4].y), pk2(t2v[5].x,t2v[5].y),
            pk2(t2v[6].x,t2v[6].y), pk2(t2v[7].x,t2v[7].y));
        *(uint4*)&hsb[n*12+8] = make_uint4(
            pk2(t2v[8].x,t2v[8].y), pk2(t2v[9].x,t2v[9].y),
            pk2(t2v[10].x,t2v[10].y), pk2(t2v[11].x,t2v[11].y));
        __syncthreads();   // t2 rows visible

        // ---- phase 2: B1 frags (own rows), 32 MFMAs, pack, D -> own rows ----
        uint4 b1[4];
        #pragma unroll
        for(int i=0;i<4;++i) b1[i]=make_uint4(0,0,0,0);
        if(lane < 48){
            #pragma unroll
            for(int i=0;i<4;++i){
                int nn_ = wv*64 + i*16 + (lane&15);
                b1[i] = *(const uint4*)&hsb[nn_*12 + ((lane>>4)<<2)];
            }
        }
        uint2 pa[4], pb[4];
        #pragma unroll
        for(int i=0;i<4;++i){
            f32x4 Da = {biA[0],biA[1],biA[2],biA[3]};
            f32x4 Db = {biB[0],biB[1],biB[2],biB[3]};
            Da = MF(wsHiA, b0[i], Da);
            Da = MF(wsLoA, b0[i], Da);
            Da = MF(wnHiA, b1[i], Da);
            Da = MF(wnLoA, b1[i], Da);
            Db = MF(wsHiB, b0[i], Db);
            Db = MF(wsLoB, b0[i], Db);
            Db = MF(wnHiB, b1[i], Db);
            Db = MF(wnLoB, b1[i], Db);
            pa[i] = make_uint2(pk2(Da[0],Da[1]), pk2(Da[2],Da[3]));
            pb[i] = make_uint2(pk2(Db[0],Db[1]), pk2(Db[2],Db[3]));
        }
        __syncthreads();   // all B1 reads done before D overwrites rows
        #pragma unroll
        for(int i=0;i<4;++i){
            int nn_ = wv*64 + i*16 + (lane&15);
            int o = (lane>>4)*2;           // uints {0,2,4,6}: m = 2o..2o+3
            *(uint2*)&hsb[nn_*12 + o] = pa[i];
            if(lane < 32){                 // m = 16..23 -> uints {8,10}
                *(uint2*)&hsb[nn_*12 + 8 + (lane>>4)*2] = pb[i];
            }
        }
        __syncthreads();   // D visible for next layer's gather / writeback
    }
    for(int i=tid;i<1536;i+=512) ((uint4*)base)[i] = ((const uint4*)hsb)[i];
}

// ---- merged f1+f2: blocks [0,512) = f1 role, [512,1024) = f2 ----
#define F2S 25
__global__ __launch_bounds__(256) void k_f12(const unsigned* h, fp w1, fp w2,
        float* f1, float* f2){
    __shared__ float red[256*F2S];
    int tid = threadIdx.x;
    if(blockIdx.x < 512){
        // f1[b,l,n] = sum_c sg(gate)*lk(filt)*w1[c]
        if(tid < 192){
            int blk = blockIdx.x; int b = blk>>6; int n0 = (blk&63)*8;
            float acc = 0.f;
            const unsigned* fb = h + (size_t)b*CO*NT + n0*12;
            const unsigned* gb = fb + (size_t)CO*(NT/2);
            int e = tid;
            for(int c=0;c<CO;++c){
                float w = w1[c];
                unsigned f = fb[(size_t)c*(NT/2) + (e>>1)];
                unsigned g = gb[(size_t)c*(NT/2) + (e>>1)];
                float fv = (e&1) ? hi2f(f) : lo2f(f);
                float gv = (e&1) ? hi2f(g) : lo2f(g);
                acc += sg(gv)*lk(fv)*w;
            }
            int nl = e/TT, t = e%TT;
            f1[(b*TT+t)*NN + n0+nl] = acc;
        }
        return;
    }
    // f2[b,c,l] = sum_n sg(gate)*lk(filt)*w2[n]
    int blk = blockIdx.x - 512; int b = blk/CO; int c = blk%CO;
    float acc[TT];
    #pragma unroll
    for(int l=0;l<TT;++l) acc[l]=0.f;
    const unsigned* fb = h + (size_t)b*CO*NT + (size_t)c*(NT/2);
    const unsigned* gb = fb + (size_t)CO*(NT/2);
    for(int n=tid;n<NN;n+=256){
        float w = w2[n];
        #pragma unroll
        for(int k=0;k<3;++k){
            uint4 f = *(const uint4*)(fb + n*12 + 4*k);
            uint4 g = *(const uint4*)(gb + n*12 + 4*k);
            acc[8*k  ] += sg(lo2f(g.x))*lk(lo2f(f.x))*w;
            acc[8*k+1] += sg(hi2f(g.x))*lk(hi2f(f.x))*w;
            acc[8*k+2] += sg(lo2f(g.y))*lk(lo2f(f.y))*w;
            acc[8*k+3] += sg(hi2f(g.y))*lk(hi2f(f.y))*w;
            acc[8*k+4] += sg(lo2f(g.z))*lk(lo2f(f.z))*w;
            acc[8*k+5] += sg(hi2f(g.z))*lk(hi2f(f.z))*w;
            acc[8*k+6] += sg(lo2f(g.w))*lk(lo2f(f.w))*w;
            acc[8*k+7] += sg(hi2f(g.w))*lk(hi2f(f.w))*w;
        }
    }
    #pragma unroll
    for(int l=0;l<TT;++l) red[tid*F2S+l]=acc[l];
    __syncthreads();
    for(int s=128;s>0;s>>=1){
        if(tid<s){
            #pragma unroll
            for(int l=0;l<TT;++l) red[tid*F2S+l]+=red[(tid+s)*F2S+l];
        }
        __syncthreads();
    }
    if(tid<TT) f2[(b*CO+c)*TT+tid] = red[tid];
}

// ---- merged dilated convs: blocks 0..31 = conv over n on f1; 32..39 = over l on f2 ----
__global__ __launch_bounds__(256) void k_convf(fp f1, fp wd1, float* f1c,
        fp f2, fp wd2, float* f2c){
    __shared__ float sm[9856];            // union: f1 path 4272 fl, f2 path 9856 fl
    int tid=threadIdx.x;
    if(blockIdx.x < 32){
        float* fs  = sm;                  // [TT][130]
        float* w0  = sm + 3120;
        float* w1a = sm + 3696;
        int bid = blockIdx.x; int b = bid>>2; int n0 = (bid&3)*128;
        for(int i=tid;i<TT*130;i+=256){
            int l=i/130, col=i%130; int n = n0+col-1;
            fs[l*130+col] = (n>=0 && n<NN) ? f1[(b*TT+l)*NN+n] : 0.f;
        }
        for(int i=tid;i<TT*TT;i+=256){ w0[i]=wd1[i*2]; w1a[i]=wd1[i*2+1]; }
        __syncthreads();
        for(int j=tid;j<TT*128;j+=256){
            int o=j>>7, nn=j&127;
            float acc=0.f;
            #pragma unroll
            for(int i=0;i<TT;++i) acc += fs[i*130+nn]*w0[o*TT+i] + fs[i*130+nn+2]*w1a[o*TT+i];
            f1c[(b*TT+o)*NN+n0+nn]=acc;
        }
        return;
    }
    float* fs  = sm;                      // [CO][TT+2]
    float* w0  = sm + 1664;
    float* w1a = sm + 5760;
    int b = blockIdx.x - 32;
    for(int i=tid;i<CO*TT;i+=256){ int c=i/TT,l=i%TT; fs[c*26+l+1]=f2[(b*CO+c)*TT+l]; }
    for(int c=tid;c<CO;c+=256){ fs[c*26]=0.f; fs[c*26+TT+1]=0.f; }
    for(int i=tid;i<CO*CO;i+=256){ w0[i]=wd2[i*2]; w1a[i]=wd2[i*2+1]; }
    __syncthreads();
    for(int j=tid;j<CO*TT;j+=256){
        int o=j/TT, l=j%TT;
        float acc=0.f;
        for(int i=0;i<CO;++i) acc += fs[i*26+l]*w0[o*CO+i] + fs[i*26+l+2]*w1a[o*CO+i];
        f2c[(b*CO+o)*TT+l]=acc;
    }
}

// ---------------- g1[b,l,c] = sum_n f1c[b,l,n]*tW[n,c] ----------------
__global__ __launch_bounds__(384) void k_g1(fp f1c, fp tW, float* g1){
    __shared__ float fs[6*NN];
    int blk=blockIdx.x; int b=blk>>2; int part=blk&3;
    int tid=threadIdx.x;
    for(int i=tid;i<6*NN;i+=384) fs[i]=f1c[b*TT*NN + part*6*NN + i];
    __syncthreads();
    int c = tid & 63; int r = tid >> 6;   // r = 0..5
    float acc=0.f;
    for(int n=0;n<NN;++n) acc += fs[r*NN + n]*tW[n*CO + c];
    g1[(b*TT + part*6 + r)*CO + c] = acc;
}

// -------- logits: A = sig matmul (18 blk); BC = t_v matmul + BN + softmax (1 blk) --
__global__ __launch_bounds__(256) void k_lgA(fp g1, fp f2c, fp tbias, float* sig){
    int j = blockIdx.x*256 + threadIdx.x;
    int b=j/(TT*TT); int r=j%(TT*TT); int l=r/TT; int q=r%TT;
    float acc = tbias[l*TT+q];
    fp gg = g1 + (b*TT+l)*CO;
    fp ff = f2c + b*CO*TT + q;
    for(int c=0;c<CO;++c) acc += gg[c]*ff[c*TT];
    sig[j] = sg(acc);
}
__global__ __launch_bounds__(256) void k_lgBC(fp tv, const float* sig,
        fp bng, fp bnb, float* coefs, float* tco){
    __shared__ float lg2[B_*TT*TT];       // 18.4 KB
    __shared__ float muq[TT], scq[TT], shq[TT];
    int tid=threadIdx.x;
    for(int j=tid;j<B_*TT*TT;j+=256){
        int b=j/(TT*TT); int r=j%(TT*TT); int l=r/TT; int q=r%TT;
        float acc=0.f;
        for(int k=0;k<TT;++k) acc += tv[l*TT+k]*sig[(b*TT+k)*TT+q];
        lg2[j]=acc;
    }
    __syncthreads();
    if(tid<TT){
        int q=tid;
        float s=0.f;
        for(int b=0;b<B_;++b) for(int l=0;l<TT;++l) s += lg2[(b*TT+l)*TT+q];
        float mu = s/192.f;
        float v=0.f;
        for(int b=0;b<B_;++b) for(int l=0;l<TT;++l){ float d = lg2[(b*TT+l)*TT+q]-mu; v += d*d; }
        v = fmaxf(v/192.f, 0.f);
        muq[q]=mu; scq[q]=rsqrtf(v+EPSL)*bng[q]; shq[q]=bnb[q];
    }
    __syncthreads();
    if(tid<192){
        int b=tid/TT, l=tid%TT;
        int base = (l<12)?0:12;
        float z[12];
        float mx=-1e30f;
        #pragma unroll
        for(int r=0;r<12;++r){
            int q=base+r;
            float zv=(lg2[(b*TT+l)*TT+q]-muq[q])*scq[q]+shq[q];
            z[r]=zv; mx = fmaxf(mx,zv);
        }
        float s=0.f;
        #pragma unroll
        for(int r=0;r<12;++r){ z[r]=expf(z[r]-mx); s+=z[r]; }
        float is=1.f/s;
        for(int q=0;q<TT;++q){
            float cf = (q>=base && q<base+12) ? z[q-base]*is : 0.f;
            coefs[(b*TT+l)*TT+q]=cf;
            tco[(b*TT+q)*TT+l]=cf;
        }
    }
}

// ---- x1new = xg @ coefs^T ; y = leaky(x1new)+x_input ; LN stats ----
// Round 15: Y stored as PACKED BF16 (uint pairs) — halves the 50MB write and
// k_final's 50MB read. LN stats still accumulate from full-fp32 y; only the
// stored copy is rounded (error ~2^-9 of normalized scale, << 0.12 threshold).
__global__ __launch_bounds__(256, 4) void k_apply(const unsigned* h, fp xin, fp coefs,
        unsigned* y, float* stats){
    __shared__ __attribute__((aligned(16))) float cf[TT*TT];
    __shared__ float red[256];
    int blk=blockIdx.x; int b=blk>>7; int c=(blk>>1)&63; int half=blk&1;
    int tid=threadIdx.x;
    for(int i=tid;i<TT*TT;i+=256) cf[i]=coefs[b*TT*TT+i];
    __syncthreads();
    int n = half*256 + tid;
    const unsigned* fb = h + (size_t)b*CO*NT + (size_t)c*(NT/2) + n*12;
    const unsigned* gb = fb + (size_t)CO*(NT/2);
    fp xrow = xin + (size_t)(b*CO+c)*NT + n*TT;
    unsigned* yrow = y + (size_t)(b*CO+c)*(NT/2) + n*12;
    float row[TT];
    #pragma unroll
    for(int k=0;k<3;++k){
        uint4 f = *(const uint4*)(fb + 4*k);
        uint4 g = *(const uint4*)(gb + 4*k);
        row[8*k  ] = sg(lo2f(g.x))*lk(lo2f(f.x));
        row[8*k+1] = sg(hi2f(g.x))*lk(hi2f(f.x));
        row[8*k+2] = sg(lo2f(g.y))*lk(lo2f(f.y));
        row[8*k+3] = sg(hi2f(g.y))*lk(hi2f(f.y));
        row[8*k+4] = sg(lo2f(g.z))*lk(lo2f(f.z));
        row[8*k+5] = sg(hi2f(g.z))*lk(hi2f(f.z));
        row[8*k+6] = sg(lo2f(g.w))*lk(lo2f(f.w));
        row[8*k+7] = sg(hi2f(g.w))*lk(hi2f(f.w));
    }
    float ls=0.f, lsq=0.f;
    #pragma unroll
    for(int k=0;k<6;++k){
        float4 u = *(const float4*)(xrow + 4*k);
        float a[4];
        #pragma unroll
        for(int j=0;j<4;++j){
            const float4* crow = (const float4*)&cf[(4*k+j)*TT];
            float acc=0.f;
            #pragma unroll
            for(int kk=0;kk<6;++kk){
                float4 cv = crow[kk];
                acc += row[4*kk  ]*cv.x;
                acc += row[4*kk+1]*cv.y;
                acc += row[4*kk+2]*cv.z;
                acc += row[4*kk+3]*cv.w;
            }
            a[j]=acc;
        }
        float y0 = lk(a[0])+u.x, y1 = lk(a[1])+u.y, y2 = lk(a[2])+u.z, y3 = lk(a[3])+u.w;
        *(uint2*)(yrow + 2*k) = make_uint2(pk2(y0,y1), pk2(y2,y3));
        ls  += y0+y1+y2+y3;
        lsq += y0*y0+y1*y1+y2*y2+y3*y3;
    }
    red[tid]=ls; __syncthreads();
    for(int s=128;s>0;s>>=1){ if(tid<s) red[tid]+=red[tid+s]; __syncthreads(); }
    float t0=red[0]; __syncthreads();
    red[tid]=lsq; __syncthreads();
    for(int s=128;s>0;s>>=1){ if(tid<s) red[tid]+=red[tid+s]; __syncthreads(); }
    if(tid==0){ atomicAdd(&stats[32+b], t0); atomicAdd(&stats[40+b], red[0]); }
}

// ---- final LN apply; stats finalize inlined; bf16 Y input, uint4 vectorized ----
__global__ void k_final(const unsigned* y, fp lng, fp lnb, const float* stats, float* out){
    float mb[8], sb[8];
    #pragma unroll
    for(int b=0;b<8;++b){
        float mm = stats[32+b] / (float)LNCNT;
        float vv = fmaxf(stats[40+b] / (float)LNCNT - mm*mm, 0.f);
        mb[b]=mm; sb[b]=rsqrtf(vv + EPSL);
    }
    int tot8 = B_*CO*NT/8;
    for(int i = blockIdx.x*blockDim.x + threadIdx.x; i<tot8; i+=gridDim.x*blockDim.x){
        int e = i*8;
        int b = e/LNCNT; int r = e%LNCNT;
        uint4 u = *(const uint4*)(y + (e>>1));
        float4 g0 = *(const float4*)(lng + r);
        float4 g1 = *(const float4*)(lng + r + 4);
        float4 b0 = *(const float4*)(lnb + r);
        float4 b1 = *(const float4*)(lnb + r + 4);
        float m = mb[b], s = sb[b];
        *(float4*)(out + e) = make_float4(
            (lo2f(u.x)-m)*s*g0.x+b0.x, (hi2f(u.x)-m)*s*g0.y+b0.y,
            (lo2f(u.y)-m)*s*g0.z+b0.z, (hi2f(u.y)-m)*s*g0.w+b0.w);
        *(float4*)(out + e + 4) = make_float4(
            (lo2f(u.z)-m)*s*g1.x+b1.x, (hi2f(u.z)-m)*s*g1.y+b1.y,
            (lo2f(u.w)-m)*s*g1.z+b1.z, (hi2f(u.w)-m)*s*g1.w+b1.w);
    }
}

extern "C" void kernel_launch(void* const* d_in, const int* in_sizes, int n_in,
                              void* d_out, int out_size, void* d_ws, size_t ws_size,
                              hipStream_t stream){
    fp x    = (fp)d_in[0];
    fp adj  = (fp)d_in[1];
    fp w1   = (fp)d_in[2];
    fp b1   = (fp)d_in[3];
    fp wt   = (fp)d_in[4];
    fp bt   = (fp)d_in[5];
    fp lng  = (fp)d_in[6];
    fp lnb  = (fp)d_in[7];
    fp s0ws = (fp)d_in[8];
    fp s0wn = (fp)d_in[9];
    fp s0b  = (fp)d_in[10];
    fp s1ws = (fp)d_in[11];
    fp s1wn = (fp)d_in[12];
    fp s1b  = (fp)d_in[13];
    fp tw1  = (fp)d_in[14];
    fp tw2  = (fp)d_in[15];
    fp twd1 = (fp)d_in[16];
    fp twd2 = (fp)d_in[17];
    fp tW   = (fp)d_in[18];
    fp tbias= (fp)d_in[19];
    fp tv   = (fp)d_in[20];
    fp bng  = (fp)d_in[21];
    fp bnb  = (fp)d_in[22];

    float* W = (float*)d_ws;            // stats [0..63]
    int*   CNTp = (int*)(W+256);        // 512 ints
    int*   PERM = (int*)(W+768);        // 512 ints
    int*   IDXp = (int*)(W+1280);
    float* VALp = W+34048;
    float* F1   = W+66816;
    float* F1C  = W+165120;
    float* F2   = W+263424;
    float* F2C  = W+275712;
    float* G1   = W+288000;
    float* CF   = W+300288;
    float* XIN  = W+304896;
    float* X1   = W+6596352;
    float* SIG  = W+6596352;            // reuse X1 head (dead after hbuild)
    uint4* WFq  = (uint4*)(W+12887808); // sage weight frags: 1024 uint4 = 16KB
    uint4* WCF  = (uint4*)(W+12891904); // conv weight frags: 2048 uint4 = 32KB
    unsigned* HA = (unsigned*)(W+19179264);   // packed bf16 h: 6291456 uints
    unsigned* Yp = (unsigned*)(W+31762176);   // packed bf16 y: 3145728 uints
    float* LG2  = SIG + 4608;

    float* oout   = (float*)d_out;
    float* o_adj  = oout + 6291456;
    float* o_tc   = oout + 6291456 + 262144;

    hipMemsetAsync(W, 0, 768*sizeof(float), stream);   // stats + cnt
    k_cscw<<<1025,256,0,stream>>>(adj, CNTp, IDXp, VALp, o_adj,
                                  s0ws, s0wn, s1ws, s1wn, WFq, w1, wt, WCF);
    k_perm<<<1,512,0,stream>>>(CNTp, PERM);
    k_conv<<<512,256,0,stream>>>(x, WCF, b1, bt, XIN, X1, W);
    k_hbuild<<<512,512,0,stream>>>(X1, lng, lnb, W, CNTp, IDXp, VALp, PERM, HA);
    k_sageF<<<1024,512,0,stream>>>(HA, WFq, s0b, s1b, CNTp, IDXp, PERM);
    k_f12<<<1024,256,0,stream>>>(HA, tw1, tw2, F1, F2);
    k_convf<<<40,256,0,stream>>>(F1, twd1, F1C, F2, twd2, F2C);
    k_g1<<<32,384,0,stream>>>(F1C, tW, G1);
    k_lgA<<<18,256,0,stream>>>(G1, F2C, tbias, SIG);
    k_lgBC<<<1,256,0,stream>>>(tv, SIG, bng, bnb, CF, o_tc);
    k_apply<<<1024,256,0,stream>>>(HA, XIN, CF, Yp, W);
    k_final<<<2048,256,0,stream>>>(Yp, lng, lnb, W, oout);
}